// Round 5
// baseline (656.222 us; speedup 1.0000x reference)
//
#include <hip/hip_runtime.h>
#include <stdint.h>

typedef __attribute__((ext_vector_type(8))) short short8;
typedef __attribute__((ext_vector_type(4))) float f32x4;

#define NN 1024
#define NBATCH 16384

__device__ __forceinline__ unsigned short f32_to_bf16_rne(float f) {
  unsigned int u = __float_as_uint(f);
  unsigned int r = (u + 0x7fffu + ((u >> 16) & 1u)) >> 16;
  return (unsigned short)r;
}

__device__ __forceinline__ unsigned int pack2bf(float lo, float hi) {
  return (unsigned int)f32_to_bf16_rne(lo) | ((unsigned int)f32_to_bf16_rne(hi) << 16);
}

// 64-lane all-reduce sum: 4 DPP (VALU) stages + ds_swizzle xor16 + shfl xor32.
__device__ __forceinline__ float allsum64(float x) {
  x += __int_as_float(__builtin_amdgcn_update_dpp(0, __float_as_int(x), 0xB1, 0xF, 0xF, true));   // xor1
  x += __int_as_float(__builtin_amdgcn_update_dpp(0, __float_as_int(x), 0x4E, 0xF, 0xF, true));   // xor2
  x += __int_as_float(__builtin_amdgcn_update_dpp(0, __float_as_int(x), 0x141, 0xF, 0xF, true));  // xor4 (row_half_mirror)
  x += __int_as_float(__builtin_amdgcn_update_dpp(0, __float_as_int(x), 0x140, 0xF, 0xF, true));  // xor8 (row_mirror)
  x += __int_as_float(__builtin_amdgcn_ds_swizzle(__float_as_int(x), 0x401F));                    // xor16
  x += __shfl_xor(x, 32);
  return x;
}

// -------------------- prep: tau = 2/(u.u), sigmas --------------------
__global__ __launch_bounds__(256) void prep_kernel(
    const float* __restrict__ U, const float* __restrict__ V,
    const float* __restrict__ p, float* __restrict__ tau_u,
    float* __restrict__ tau_v, float* __restrict__ sigmas) {
  int wave = threadIdx.x >> 6, lane = threadIdx.x & 63;
  int row = blockIdx.x * 4 + wave;
  if (row < 2048) {
    const float* u = (row < NN) ? (U + (size_t)row * NN) : (V + (size_t)(row - NN) * NN);
    float s = 0.f;
#pragma unroll
    for (int t = 0; t < 16; ++t) { float a = u[lane + (t << 6)]; s += a * a; }
    s = allsum64(s);
    if (lane == 0) {
      float tau = 2.0f / s;
      if (row < NN) tau_u[row] = tau;
      else tau_v[row - NN] = tau;
    }
  } else if (row < 2064) {
    int j = ((row - 2048) << 6) + lane;
    float pj = p[j];
    float sg = 1.0f / (1.0f + expf(-pj));
    sigmas[j] = 0.9f * (sg - 0.5f) + 0.55f;  // r=0.45, mean=0.55
  }
}

// -------------------- gram + T8 per block of 8 reflectors --------------------
// blk<128: U bank, rows 8*blk+j (j=0..7). blk>=128: s=blk-128, V bank, rows 1023-8s-j.
__global__ __launch_bounds__(64) void gram_t8_kernel(
    const float* __restrict__ U, const float* __restrict__ V,
    const float* __restrict__ tau_u, const float* __restrict__ tau_v,
    float* __restrict__ T8all) {
  __shared__ float G[64];
  const int blk = blockIdx.x;
  const int lane = threadIdx.x;
  const float* bank;
  int rbase, rsign, st;
  if (blk < 128) { bank = U; rbase = 8 * blk; rsign = 1; st = 8 * blk; }
  else { int s = blk - 128; bank = V; rbase = 1023 - 8 * s; rsign = -1; st = 1016 - 8 * s; }

  if (lane < 28) {
    int j = 1, k = 0, t = lane;
    for (int jj = 1; jj < 8; ++jj) {
      int lo = jj * (jj - 1) / 2, hi = jj * (jj + 1) / 2;
      if (t >= lo && t < hi) { j = jj; k = t - lo; }
    }
    const float* rk = bank + (size_t)(rbase + rsign * k) * NN;
    const float* rj = bank + (size_t)(rbase + rsign * j) * NN;
    float acc = 0.f;
    for (int i = st >> 2; i < 256; ++i) {
      float4 a = *reinterpret_cast<const float4*>(rk + 4 * i);
      float4 b = *reinterpret_cast<const float4*>(rj + 4 * i);
      acc += a.x * b.x + a.y * b.y + a.z * b.z + a.w * b.w;
    }
    G[k * 8 + j] = acc;
  }
  __syncthreads();

  if (lane < 8) {
    float Tr[8];
#pragma unroll
    for (int j = 0; j < 8; ++j) Tr[j] = 0.f;
#pragma unroll
    for (int j = 0; j < 8; ++j) {
      int grow = rbase + rsign * j;
      float tj = (blk < 128) ? tau_u[grow] : tau_v[grow];
      float a = 0.f;
#pragma unroll
      for (int k = 0; k < 8; ++k) {
        if (k < j) a += Tr[k] * G[k * 8 + j];
      }
      Tr[j] = (lane == j) ? tj : (-tj * a);
    }
#pragma unroll
    for (int j = 0; j < 8; ++j) T8all[(size_t)blk * 64 + lane * 8 + j] = Tr[j];
  }
}

// -------------------- build 4 half-chains: 512 blocks x 512 threads --------------------
// chain 0: Alo = H_u0..H_u511      (asc,  q0 segs {0,1}),  store row-major
// chain 1: Ahi = H_u512..H_u1023   (asc,  q0 segs {2,3}),  store transposed
// chain 2: Bhi = H_v1023..H_v512   (desc, q0 segs {3,2}),  store row-major
// chain 3: Blo = H_v511..H_v0      (desc, q0 segs {1,0}),  store transposed
// Element map: v[4q+r] holds e = 256q + 4*lane + r. Wave w owns row (bid&127)*8+w
// and stages reflector slot w's 4 quarters.
__device__ __forceinline__ void stage4(int chain, int step, float* lbuf, float* tbuf,
    const float* __restrict__ U, const float* __restrict__ V,
    const float* __restrict__ T8all, int wave, int lane) {
  if (step >= 64) return;
  int q0, rbase, rsign, t8i;
  const float* bank;
  switch (chain) {
    case 0:  q0 = step >> 5;              bank = U; rbase = 8 * step;        rsign = 1;  t8i = step;       break;
    case 1:  q0 = 2 + (step >> 5);        bank = U; rbase = 512 + 8 * step;  rsign = 1;  t8i = 64 + step;  break;
    case 2:  q0 = (1016 - 8 * step) >> 8; bank = V; rbase = 1023 - 8 * step; rsign = -1; t8i = 128 + step; break;
    default: q0 = (504 - 8 * step) >> 8;  bank = V; rbase = 511 - 8 * step;  rsign = -1; t8i = 192 + step; break;
  }
  const int grow = rbase + rsign * wave;
  const float* gbase = bank + (size_t)grow * NN;
  float* lrow = lbuf + wave * NN;
#pragma unroll
  for (int q = 0; q < 4; ++q) {
    if (q < q0) continue;
    __builtin_amdgcn_global_load_lds(
        (const __attribute__((address_space(1))) void*)(gbase + q * 256 + lane * 4),
        (__attribute__((address_space(3))) void*)(lrow + q * 256), 16, 0, 0);
  }
  if (wave == 0 && lane < 16) {
    float4 t = *reinterpret_cast<const float4*>(T8all + (size_t)t8i * 64 + lane * 4);
    *reinterpret_cast<float4*>(tbuf + lane * 4) = t;
  }
}

// Two-pass WY-8 application: no register u-cache (R4's uc[8][16] spilled to
// scratch -> 870 MB/dispatch of HBM write traffic). LDS traffic doubles but
// stays well under the 256 B/clk/CU LDS ceiling; VGPR ~60.
template <int Q0>
__device__ __forceinline__ void apply_block(const float* __restrict__ ub,
    const float* __restrict__ tb, float* __restrict__ v, int lane) {
  float c[8];
  // pass 1: dots
#pragma unroll
  for (int j = 0; j < 8; ++j) {
    float acc = 0.f;
#pragma unroll
    for (int q = Q0; q < 4; ++q) {
      const float4 uu = *reinterpret_cast<const float4*>(&ub[j * NN + q * 256 + lane * 4]);
      acc += uu.x * v[4 * q + 0] + uu.y * v[4 * q + 1] +
             uu.z * v[4 * q + 2] + uu.w * v[4 * q + 3];
    }
    c[j] = acc;
  }
#pragma unroll
  for (int j = 0; j < 8; ++j) c[j] = allsum64(c[j]);
  // w = (lower-tri T^T) apply
  float w[8];
#pragma unroll
  for (int j = 0; j < 8; ++j) {
    float acc = 0.f;
#pragma unroll
    for (int k = 0; k < 8; ++k) {
      if (k <= j) acc += c[k] * tb[k * 8 + j];
    }
    w[j] = acc;
  }
  // pass 2: update (re-read u from LDS; q outer to keep v[.] register-resident)
#pragma unroll
  for (int q = Q0; q < 4; ++q) {
    float a0 = v[4 * q + 0], a1 = v[4 * q + 1], a2 = v[4 * q + 2], a3 = v[4 * q + 3];
#pragma unroll
    for (int j = 0; j < 8; ++j) {
      const float4 uu = *reinterpret_cast<const float4*>(&ub[j * NN + q * 256 + lane * 4]);
      a0 -= w[j] * uu.x; a1 -= w[j] * uu.y; a2 -= w[j] * uu.z; a3 -= w[j] * uu.w;
    }
    v[4 * q + 0] = a0; v[4 * q + 1] = a1; v[4 * q + 2] = a2; v[4 * q + 3] = a3;
  }
}

__global__ __launch_bounds__(512, 4) void build4_kernel(
    const float* __restrict__ U, const float* __restrict__ V,
    const float* __restrict__ T8all,
    unsigned short* __restrict__ Alo, unsigned short* __restrict__ S1,
    unsigned short* __restrict__ Bhi, unsigned short* __restrict__ S3) {
  __shared__ float ubuf[2][8 * NN];
  __shared__ float tbuf[2][64];
  const int tid = threadIdx.x;
  const int wave = tid >> 6, lane = tid & 63;
  const int chain = blockIdx.x >> 7;
  const int row = ((blockIdx.x & 127) << 3) + wave;

  float v[16];
#pragma unroll
  for (int q = 0; q < 4; ++q)
#pragma unroll
    for (int r = 0; r < 4; ++r)
      v[4 * q + r] = (256 * q + 4 * lane + r == row) ? 1.0f : 0.0f;

  stage4(chain, 0, ubuf[0], tbuf[0], U, V, T8all, wave, lane);
  int pb = 0;

#define SEG(Q0C, BASE)                                                            \
  for (int s = 0; s < 32; ++s) {                                                  \
    const int step = (BASE) + s;                                                  \
    __syncthreads(); /* vmcnt drained: staged buf ready, prev buf consumed */     \
    stage4(chain, step + 1, ubuf[pb ^ 1], tbuf[pb ^ 1], U, V, T8all, wave, lane); \
    apply_block<Q0C>(ubuf[pb], tbuf[pb], v, lane);                                \
    pb ^= 1;                                                                      \
  }

  if (chain == 0)      { SEG(0, 0) SEG(1, 32) }
  else if (chain == 1) { SEG(2, 0) SEG(3, 32) }
  else if (chain == 2) { SEG(3, 0) SEG(2, 32) }
  else                 { SEG(1, 0) SEG(0, 32) }
#undef SEG

  if (chain == 0 || chain == 2) {
    unsigned short* dst = (chain == 0) ? Alo : Bhi;
#pragma unroll
    for (int q = 0; q < 4; ++q) {
      ushort4 pk;
      pk.x = f32_to_bf16_rne(v[4 * q + 0]);
      pk.y = f32_to_bf16_rne(v[4 * q + 1]);
      pk.z = f32_to_bf16_rne(v[4 * q + 2]);
      pk.w = f32_to_bf16_rne(v[4 * q + 3]);
      *reinterpret_cast<ushort4*>(&dst[(size_t)row * NN + 256 * q + 4 * lane]) = pk;
    }
  } else {
    unsigned short* dst = (chain == 1) ? S1 : S3;
#pragma unroll
    for (int q = 0; q < 4; ++q)
#pragma unroll
      for (int r = 0; r < 4; ++r)
        dst[(size_t)(256 * q + 4 * lane + r) * NN + row] = f32_to_bf16_rne(v[4 * q + r]);
  }
}

// -------------------- generic 1024^3 bf16 compose: D[m][n] = sum_k X[m][k]*W[n][k] --------------------
#define BM 128
#define BN 128
#define BK 32
#define LDK 40

__device__ __forceinline__ void compose_body(
    const unsigned short* __restrict__ Xb, const unsigned short* __restrict__ Wb,
    unsigned short* __restrict__ Op, const float* __restrict__ sig, int b) {
  __shared__ unsigned short As[BM * LDK];
  __shared__ unsigned short Bs[BN * LDK];
  const int tid = threadIdx.x;
  const int lane = tid & 63, wave = tid >> 6;
  const int bm = b & 7, bn = b >> 3;
  const int m0 = bm * BM, n0 = bn * BN;
  const int wm = wave & 1, wn = wave >> 1;

  const int srow = tid >> 1;
  const int scol = (tid & 1) << 4;
  const unsigned short* aptr = Xb + (size_t)(m0 + srow) * NN + scol;
  const unsigned short* bptr = Wb + (size_t)(n0 + srow) * NN + scol;

  f32x4 acc[4][4];
#pragma unroll
  for (int a = 0; a < 4; ++a)
#pragma unroll
    for (int bb = 0; bb < 4; ++bb) acc[a][bb] = 0.f;

  uint4 ra0 = *reinterpret_cast<const uint4*>(aptr + 0);
  uint4 ra1 = *reinterpret_cast<const uint4*>(aptr + 8);
  uint4 rb0 = *reinterpret_cast<const uint4*>(bptr + 0);
  uint4 rb1 = *reinterpret_cast<const uint4*>(bptr + 8);

  const int arow0 = wm * 64;
  const int brow0 = wn * 64;
  const int fr = lane & 15;
  const int kb = (lane >> 4) << 3;

#pragma unroll 1
  for (int kt = 0; kt < NN / BK; ++kt) {
    __syncthreads();
    *reinterpret_cast<uint4*>(&As[srow * LDK + scol]) = ra0;
    *reinterpret_cast<uint4*>(&As[srow * LDK + scol + 8]) = ra1;
    *reinterpret_cast<uint4*>(&Bs[srow * LDK + scol]) = rb0;
    *reinterpret_cast<uint4*>(&Bs[srow * LDK + scol + 8]) = rb1;
    __syncthreads();
    if (kt + 1 < NN / BK) {
      const unsigned short* ap = aptr + (kt + 1) * BK;
      const unsigned short* bp = bptr + (kt + 1) * BK;
      ra0 = *reinterpret_cast<const uint4*>(ap + 0);
      ra1 = *reinterpret_cast<const uint4*>(ap + 8);
      rb0 = *reinterpret_cast<const uint4*>(bp + 0);
      rb1 = *reinterpret_cast<const uint4*>(bp + 8);
    }
    short8 af[4], bf[4];
#pragma unroll
    for (int tr = 0; tr < 4; ++tr)
      af[tr] = *reinterpret_cast<const short8*>(&As[(arow0 + tr * 16 + fr) * LDK + kb]);
#pragma unroll
    for (int tc = 0; tc < 4; ++tc)
      bf[tc] = *reinterpret_cast<const short8*>(&Bs[(brow0 + tc * 16 + fr) * LDK + kb]);
#pragma unroll
    for (int tr = 0; tr < 4; ++tr)
#pragma unroll
      for (int tc = 0; tc < 4; ++tc)
        acc[tr][tc] = __builtin_amdgcn_mfma_f32_16x16x32_bf16(af[tr], bf[tc], acc[tr][tc], 0, 0, 0);
  }

  const int rq = (lane >> 4) << 2;
#pragma unroll
  for (int tc = 0; tc < 4; ++tc) {
    const int gc = n0 + brow0 + tc * 16 + fr;
    const float s = sig ? sig[gc] : 1.0f;
#pragma unroll
    for (int tr = 0; tr < 4; ++tr) {
      const int gr = m0 + arow0 + tr * 16 + rq;
#pragma unroll
      for (int q = 0; q < 4; ++q) {
        Op[(size_t)(gr + q) * NN + gc] = f32_to_bf16_rne(acc[tr][tc][q] * s);
      }
    }
  }
}

// #1 and #2 fused (independent): 128 blocks.
__global__ __launch_bounds__(256) void composeAB_kernel(
    const unsigned short* __restrict__ Alo, const unsigned short* __restrict__ S1,
    const unsigned short* __restrict__ Bhi, const unsigned short* __restrict__ S3,
    const float* __restrict__ sigmas,
    unsigned short* __restrict__ Asig, unsigned short* __restrict__ Bt2) {
  const int b = blockIdx.x;
  if (b < 64) {
    // Asig[k][j] = (sum_m Alo[k][m] * Ahi[m][j]) * sigma_j ; S1[j][m] = Ahi[m][j]
    compose_body(Alo, S1, Asig, sigmas, b);
  } else {
    // Bt2[n][j] = sum_m Blo[m][n] * Bhi[j][m] = B[j][n] ; S3[n][m] = Blo[m][n]
    compose_body(S3, Bhi, Bt2, nullptr, b - 64);
  }
}

// #3: Mt[n][k] = sum_j Bt2[n][j] * Asig[k][j]. 64 blocks.
__global__ __launch_bounds__(256) void composeMt_kernel(
    const unsigned short* __restrict__ Bt2, const unsigned short* __restrict__ Asig,
    unsigned short* __restrict__ Mt) {
  compose_body(Bt2, Asig, Mt, nullptr, blockIdx.x);
}

// -------------------- GEMM: out = x @ M + bias (X f32 -> bf16 on the fly) ----
__global__ __launch_bounds__(256) void gemm_kernel(
    const float* __restrict__ X, const unsigned short* __restrict__ Mt,
    const float* __restrict__ bias, float* __restrict__ Out) {
  __shared__ unsigned short As[BM * LDK];
  __shared__ unsigned short Bs[BN * LDK];
  const int tid = threadIdx.x;
  const int lane = tid & 63, wave = tid >> 6;
  const int bm = blockIdx.x & 127;
  const int bn = blockIdx.x >> 7;
  const int m0 = bm * BM, n0 = bn * BN;
  const int wm = wave & 1, wn = wave >> 1;

  const int srow = tid >> 1;
  const int scol = (tid & 1) << 4;
  const float* aptr = X + (size_t)(m0 + srow) * NN + scol;
  const unsigned short* bptr = Mt + (size_t)(n0 + srow) * NN + scol;

  f32x4 acc[4][4];
#pragma unroll
  for (int a = 0; a < 4; ++a)
#pragma unroll
    for (int b = 0; b < 4; ++b) acc[a][b] = 0.f;

  float4 ra0 = *reinterpret_cast<const float4*>(aptr + 0);
  float4 ra1 = *reinterpret_cast<const float4*>(aptr + 4);
  float4 ra2 = *reinterpret_cast<const float4*>(aptr + 8);
  float4 ra3 = *reinterpret_cast<const float4*>(aptr + 12);
  uint4 rb0 = *reinterpret_cast<const uint4*>(bptr + 0);
  uint4 rb1 = *reinterpret_cast<const uint4*>(bptr + 8);

  const int arow0 = wm * 64;
  const int brow0 = wn * 64;
  const int fr = lane & 15;
  const int kb = (lane >> 4) << 3;

#pragma unroll 1
  for (int kt = 0; kt < NN / BK; ++kt) {
    __syncthreads();
    uint4 w0, w1;
    w0.x = pack2bf(ra0.x, ra0.y); w0.y = pack2bf(ra0.z, ra0.w);
    w0.z = pack2bf(ra1.x, ra1.y); w0.w = pack2bf(ra1.z, ra1.w);
    w1.x = pack2bf(ra2.x, ra2.y); w1.y = pack2bf(ra2.z, ra2.w);
    w1.z = pack2bf(ra3.x, ra3.y); w1.w = pack2bf(ra3.z, ra3.w);
    *reinterpret_cast<uint4*>(&As[srow * LDK + scol]) = w0;
    *reinterpret_cast<uint4*>(&As[srow * LDK + scol + 8]) = w1;
    *reinterpret_cast<uint4*>(&Bs[srow * LDK + scol]) = rb0;
    *reinterpret_cast<uint4*>(&Bs[srow * LDK + scol + 8]) = rb1;
    __syncthreads();
    if (kt + 1 < NN / BK) {
      const float* ap = aptr + (kt + 1) * BK;
      const unsigned short* bp = bptr + (kt + 1) * BK;
      ra0 = *reinterpret_cast<const float4*>(ap + 0);
      ra1 = *reinterpret_cast<const float4*>(ap + 4);
      ra2 = *reinterpret_cast<const float4*>(ap + 8);
      ra3 = *reinterpret_cast<const float4*>(ap + 12);
      rb0 = *reinterpret_cast<const uint4*>(bp + 0);
      rb1 = *reinterpret_cast<const uint4*>(bp + 8);
    }
    short8 af[4], bf[4];
#pragma unroll
    for (int tr = 0; tr < 4; ++tr)
      af[tr] = *reinterpret_cast<const short8*>(&As[(arow0 + tr * 16 + fr) * LDK + kb]);
#pragma unroll
    for (int tc = 0; tc < 4; ++tc)
      bf[tc] = *reinterpret_cast<const short8*>(&Bs[(brow0 + tc * 16 + fr) * LDK + kb]);
#pragma unroll
    for (int tr = 0; tr < 4; ++tr)
#pragma unroll
      for (int tc = 0; tc < 4; ++tc)
        acc[tr][tc] = __builtin_amdgcn_mfma_f32_16x16x32_bf16(af[tr], bf[tc], acc[tr][tc], 0, 0, 0);
  }

  const int rq = (lane >> 4) << 2;
#pragma unroll
  for (int tc = 0; tc < 4; ++tc) {
    const int gc = n0 + brow0 + tc * 16 + fr;
    const float bv = bias[gc];
#pragma unroll
    for (int tr = 0; tr < 4; ++tr) {
      const int gr = m0 + arow0 + tr * 16 + rq;
#pragma unroll
      for (int q = 0; q < 4; ++q) {
        Out[(size_t)(gr + q) * NN + gc] = acc[tr][tc][q] + bv;
      }
    }
  }
}

extern "C" void kernel_launch(void* const* d_in, const int* in_sizes, int n_in,
                              void* d_out, int out_size, void* d_ws, size_t ws_size,
                              hipStream_t stream) {
  const float* x = (const float*)d_in[0];
  const float* U = (const float*)d_in[1];
  const float* V = (const float*)d_in[2];
  const float* p = (const float*)d_in[3];
  const float* bias = (const float*)d_in[4];
  float* out = (float*)d_out;

  char* ws = (char*)d_ws;
  float* tau_u = (float*)(ws);
  float* tau_v = (float*)(ws + 4096);
  float* sigmas = (float*)(ws + 8192);
  float* T8all = (float*)(ws + 16384);                 // 64 KB
  unsigned short* Mt = (unsigned short*)(ws + 81920);  // 2 MB (must survive until gemm)

  // Large temporaries live in d_out (64 MB) and are fully consumed before gemm
  // overwrites d_out. 6 matrices x 1M bf16 elements = 12 MB.
  unsigned short* sc = (unsigned short*)d_out;
  const size_t ME = (size_t)NN * NN;
  unsigned short* Alo  = sc + 0 * ME;  // row-major  Alo[k][m]
  unsigned short* S1   = sc + 1 * ME;  // transposed S1[j][m] = Ahi[m][j]
  unsigned short* Bhi  = sc + 2 * ME;  // row-major  Bhi[j][m]
  unsigned short* S3   = sc + 3 * ME;  // transposed S3[n][m] = Blo[m][n]
  unsigned short* Asig = sc + 4 * ME;  // Asig[k][j] = A[k][j]*sigma_j
  unsigned short* Bt2  = sc + 5 * ME;  // Bt2[n][j]  = B[j][n]

  prep_kernel<<<516, 256, 0, stream>>>(U, V, p, tau_u, tau_v, sigmas);
  gram_t8_kernel<<<256, 64, 0, stream>>>(U, V, tau_u, tau_v, T8all);
  build4_kernel<<<512, 512, 0, stream>>>(U, V, T8all, Alo, S1, Bhi, S3);
  composeAB_kernel<<<128, 256, 0, stream>>>(Alo, S1, Bhi, S3, sigmas, Asig, Bt2);
  composeMt_kernel<<<64, 256, 0, stream>>>(Bt2, Asig, Mt);
  gemm_kernel<<<1024, 256, 0, stream>>>(x, Mt, bias, out);
}

// Round 6
// 494.865 us; speedup vs baseline: 1.3261x; 1.3261x over previous
//
#include <hip/hip_runtime.h>
#include <stdint.h>

typedef __attribute__((ext_vector_type(8))) short short8;
typedef __attribute__((ext_vector_type(4))) float f32x4;

#define NN 1024
#define NBATCH 16384

__device__ __forceinline__ unsigned short f32_to_bf16_rne(float f) {
  unsigned int u = __float_as_uint(f);
  unsigned int r = (u + 0x7fffu + ((u >> 16) & 1u)) >> 16;
  return (unsigned short)r;
}

__device__ __forceinline__ unsigned int pack2bf(float lo, float hi) {
  return (unsigned int)f32_to_bf16_rne(lo) | ((unsigned int)f32_to_bf16_rne(hi) << 16);
}

// 64-lane all-reduce sum: 4 DPP (VALU) stages + ds_swizzle xor16 + shfl xor32.
__device__ __forceinline__ float allsum64(float x) {
  x += __int_as_float(__builtin_amdgcn_update_dpp(0, __float_as_int(x), 0xB1, 0xF, 0xF, true));   // xor1
  x += __int_as_float(__builtin_amdgcn_update_dpp(0, __float_as_int(x), 0x4E, 0xF, 0xF, true));   // xor2
  x += __int_as_float(__builtin_amdgcn_update_dpp(0, __float_as_int(x), 0x141, 0xF, 0xF, true));  // xor4 (row_half_mirror)
  x += __int_as_float(__builtin_amdgcn_update_dpp(0, __float_as_int(x), 0x140, 0xF, 0xF, true));  // xor8 (row_mirror)
  x += __int_as_float(__builtin_amdgcn_ds_swizzle(__float_as_int(x), 0x401F));                    // xor16
  x += __shfl_xor(x, 32);
  return x;
}

// -------------------- prep: tau = 2/(u.u), sigmas --------------------
__global__ __launch_bounds__(256) void prep_kernel(
    const float* __restrict__ U, const float* __restrict__ V,
    const float* __restrict__ p, float* __restrict__ tau_u,
    float* __restrict__ tau_v, float* __restrict__ sigmas) {
  int wave = threadIdx.x >> 6, lane = threadIdx.x & 63;
  int row = blockIdx.x * 4 + wave;
  if (row < 2048) {
    const float* u = (row < NN) ? (U + (size_t)row * NN) : (V + (size_t)(row - NN) * NN);
    float s = 0.f;
#pragma unroll
    for (int t = 0; t < 16; ++t) { float a = u[lane + (t << 6)]; s += a * a; }
    s = allsum64(s);
    if (lane == 0) {
      float tau = 2.0f / s;
      if (row < NN) tau_u[row] = tau;
      else tau_v[row - NN] = tau;
    }
  } else if (row < 2064) {
    int j = ((row - 2048) << 6) + lane;
    float pj = p[j];
    float sg = 1.0f / (1.0f + expf(-pj));
    sigmas[j] = 0.9f * (sg - 0.5f) + 0.55f;  // r=0.45, mean=0.55
  }
}

// -------------------- gram + T8 per block of 8 reflectors --------------------
// blk<128: U bank, rows 8*blk+j (j=0..7). blk>=128: s=blk-128, V bank, rows 1023-8s-j.
__global__ __launch_bounds__(64) void gram_t8_kernel(
    const float* __restrict__ U, const float* __restrict__ V,
    const float* __restrict__ tau_u, const float* __restrict__ tau_v,
    float* __restrict__ T8all) {
  __shared__ float G[64];
  const int blk = blockIdx.x;
  const int lane = threadIdx.x;
  const float* bank;
  int rbase, rsign, st;
  if (blk < 128) { bank = U; rbase = 8 * blk; rsign = 1; st = 8 * blk; }
  else { int s = blk - 128; bank = V; rbase = 1023 - 8 * s; rsign = -1; st = 1016 - 8 * s; }

  if (lane < 28) {
    int j = 1, k = 0, t = lane;
    for (int jj = 1; jj < 8; ++jj) {
      int lo = jj * (jj - 1) / 2, hi = jj * (jj + 1) / 2;
      if (t >= lo && t < hi) { j = jj; k = t - lo; }
    }
    const float* rk = bank + (size_t)(rbase + rsign * k) * NN;
    const float* rj = bank + (size_t)(rbase + rsign * j) * NN;
    float acc = 0.f;
    for (int i = st >> 2; i < 256; ++i) {
      float4 a = *reinterpret_cast<const float4*>(rk + 4 * i);
      float4 b = *reinterpret_cast<const float4*>(rj + 4 * i);
      acc += a.x * b.x + a.y * b.y + a.z * b.z + a.w * b.w;
    }
    G[k * 8 + j] = acc;
  }
  __syncthreads();

  if (lane < 8) {
    float Tr[8];
#pragma unroll
    for (int j = 0; j < 8; ++j) Tr[j] = 0.f;
#pragma unroll
    for (int j = 0; j < 8; ++j) {
      int grow = rbase + rsign * j;
      float tj = (blk < 128) ? tau_u[grow] : tau_v[grow];
      float a = 0.f;
#pragma unroll
      for (int k = 0; k < 8; ++k) {
        if (k < j) a += Tr[k] * G[k * 8 + j];
      }
      Tr[j] = (lane == j) ? tj : (-tj * a);
    }
#pragma unroll
    for (int j = 0; j < 8; ++j) T8all[(size_t)blk * 64 + lane * 8 + j] = Tr[j];
  }
}

// -------------------- build 4 half-chains: 512 blocks x 256 threads, 2 rows/wave ----
// chain 0: Alo = H_u0..H_u511      (asc,  q0 segs {0,1}),  store row-major
// chain 1: Ahi = H_u512..H_u1023   (asc,  q0 segs {2,3}),  store transposed
// chain 2: Bhi = H_v1023..H_v512   (desc, q0 segs {3,2}),  store row-major
// chain 3: Blo = H_v511..H_v0      (desc, q0 segs {1,0}),  store transposed
// Element map: v[4q+r] holds e = 256q + 4*lane + r. Block (bid&127) owns rows
// base..base+7; wave w owns rows base+2w, base+2w+1 (2 rows amortize LDS reads).
// NOTE (R4/R5 lesson): do NOT pass a min-occupancy arg to __launch_bounds__ here.
// (512,4) was interpreted blocks-per-CU-style -> 64-VGPR cap -> scratch spill ->
// 755 MB/dispatch of HBM write traffic. LDS (66KB) already bounds occupancy.
__device__ __forceinline__ void stage4(int chain, int step, float* lbuf, float* tbuf,
    const float* __restrict__ U, const float* __restrict__ V,
    const float* __restrict__ T8all, int wave, int lane) {
  if (step >= 64) return;
  int q0, rbase, rsign, t8i;
  const float* bank;
  switch (chain) {
    case 0:  q0 = step >> 5;              bank = U; rbase = 8 * step;        rsign = 1;  t8i = step;       break;
    case 1:  q0 = 2 + (step >> 5);        bank = U; rbase = 512 + 8 * step;  rsign = 1;  t8i = 64 + step;  break;
    case 2:  q0 = (1016 - 8 * step) >> 8; bank = V; rbase = 1023 - 8 * step; rsign = -1; t8i = 128 + step; break;
    default: q0 = (504 - 8 * step) >> 8;  bank = V; rbase = 511 - 8 * step;  rsign = -1; t8i = 192 + step; break;
  }
#pragma unroll
  for (int c = 0; c < 8; ++c) {
    const int chunk = (wave << 3) + c;   // 4 waves x 8 chunks = 8 slots x 4 quarters
    const int slot = chunk >> 2, q = chunk & 3;
    if (q < q0) continue;
    const int grow = rbase + rsign * slot;
    const float* gsrc = bank + (size_t)grow * NN + q * 256 + lane * 4;
    float* ldst = lbuf + slot * NN + q * 256;
    __builtin_amdgcn_global_load_lds(
        (const __attribute__((address_space(1))) void*)gsrc,
        (__attribute__((address_space(3))) void*)ldst, 16, 0, 0);
  }
  if (wave == 0 && lane < 16) {
    float4 t = *reinterpret_cast<const float4*>(T8all + (size_t)t8i * 64 + lane * 4);
    *reinterpret_cast<float4*>(tbuf + lane * 4) = t;
  }
}

// Two-pass WY-8 application on TWO rows per wave: one u quarter read from LDS
// feeds both rows' dot (pass 1) and both rows' update (pass 2). No register
// u-cache (spills), LDS traffic per row halved vs 1-row version.
template <int Q0>
__device__ __forceinline__ void apply_block2(const float* __restrict__ ub,
    const float* __restrict__ tb, float* __restrict__ va, float* __restrict__ vb,
    int lane) {
  float ca[8], cb[8];
  // pass 1: dots for both rows
#pragma unroll
  for (int j = 0; j < 8; ++j) {
    float aa = 0.f, ab = 0.f;
#pragma unroll
    for (int q = Q0; q < 4; ++q) {
      const float4 uu = *reinterpret_cast<const float4*>(&ub[j * NN + q * 256 + lane * 4]);
      aa += uu.x * va[4 * q + 0] + uu.y * va[4 * q + 1] +
            uu.z * va[4 * q + 2] + uu.w * va[4 * q + 3];
      ab += uu.x * vb[4 * q + 0] + uu.y * vb[4 * q + 1] +
            uu.z * vb[4 * q + 2] + uu.w * vb[4 * q + 3];
    }
    ca[j] = aa; cb[j] = ab;
  }
#pragma unroll
  for (int j = 0; j < 8; ++j) { ca[j] = allsum64(ca[j]); cb[j] = allsum64(cb[j]); }
  // w = c * T (T upper-triangular)
  float wa[8], wb[8];
#pragma unroll
  for (int j = 0; j < 8; ++j) {
    float aa = 0.f, ab = 0.f;
#pragma unroll
    for (int k = 0; k < 8; ++k) {
      if (k <= j) { float t = tb[k * 8 + j]; aa += ca[k] * t; ab += cb[k] * t; }
    }
    wa[j] = aa; wb[j] = ab;
  }
  // pass 2: update both rows (re-read u from LDS; q outer keeps v register-resident)
#pragma unroll
  for (int q = Q0; q < 4; ++q) {
    float a0 = va[4 * q + 0], a1 = va[4 * q + 1], a2 = va[4 * q + 2], a3 = va[4 * q + 3];
    float b0 = vb[4 * q + 0], b1 = vb[4 * q + 1], b2 = vb[4 * q + 2], b3 = vb[4 * q + 3];
#pragma unroll
    for (int j = 0; j < 8; ++j) {
      const float4 uu = *reinterpret_cast<const float4*>(&ub[j * NN + q * 256 + lane * 4]);
      a0 -= wa[j] * uu.x; a1 -= wa[j] * uu.y; a2 -= wa[j] * uu.z; a3 -= wa[j] * uu.w;
      b0 -= wb[j] * uu.x; b1 -= wb[j] * uu.y; b2 -= wb[j] * uu.z; b3 -= wb[j] * uu.w;
    }
    va[4 * q + 0] = a0; va[4 * q + 1] = a1; va[4 * q + 2] = a2; va[4 * q + 3] = a3;
    vb[4 * q + 0] = b0; vb[4 * q + 1] = b1; vb[4 * q + 2] = b2; vb[4 * q + 3] = b3;
  }
}

__global__ __launch_bounds__(256) void build4_kernel(
    const float* __restrict__ U, const float* __restrict__ V,
    const float* __restrict__ T8all,
    unsigned short* __restrict__ Alo, unsigned short* __restrict__ S1,
    unsigned short* __restrict__ Bhi, unsigned short* __restrict__ S3) {
  __shared__ float ubuf[2][8 * NN];
  __shared__ float tbuf[2][64];
  const int tid = threadIdx.x;
  const int wave = tid >> 6, lane = tid & 63;
  const int chain = blockIdx.x >> 7;
  const int rowa = ((blockIdx.x & 127) << 3) + (wave << 1);
  const int rowb = rowa + 1;

  float va[16], vb[16];
#pragma unroll
  for (int q = 0; q < 4; ++q)
#pragma unroll
    for (int r = 0; r < 4; ++r) {
      const int e = 256 * q + 4 * lane + r;
      va[4 * q + r] = (e == rowa) ? 1.0f : 0.0f;
      vb[4 * q + r] = (e == rowb) ? 1.0f : 0.0f;
    }

  stage4(chain, 0, ubuf[0], tbuf[0], U, V, T8all, wave, lane);
  int pb = 0;

#define SEG(Q0C, BASE)                                                            \
  for (int s = 0; s < 32; ++s) {                                                  \
    const int step = (BASE) + s;                                                  \
    __syncthreads(); /* vmcnt drained: staged buf ready, prev buf consumed */     \
    stage4(chain, step + 1, ubuf[pb ^ 1], tbuf[pb ^ 1], U, V, T8all, wave, lane); \
    apply_block2<Q0C>(ubuf[pb], tbuf[pb], va, vb, lane);                          \
    pb ^= 1;                                                                      \
  }

  if (chain == 0)      { SEG(0, 0) SEG(1, 32) }
  else if (chain == 1) { SEG(2, 0) SEG(3, 32) }
  else if (chain == 2) { SEG(3, 0) SEG(2, 32) }
  else                 { SEG(1, 0) SEG(0, 32) }
#undef SEG

  if (chain == 0 || chain == 2) {
    unsigned short* dst = (chain == 0) ? Alo : Bhi;
#pragma unroll
    for (int q = 0; q < 4; ++q) {
      ushort4 pa, pbk;
      pa.x = f32_to_bf16_rne(va[4 * q + 0]);
      pa.y = f32_to_bf16_rne(va[4 * q + 1]);
      pa.z = f32_to_bf16_rne(va[4 * q + 2]);
      pa.w = f32_to_bf16_rne(va[4 * q + 3]);
      pbk.x = f32_to_bf16_rne(vb[4 * q + 0]);
      pbk.y = f32_to_bf16_rne(vb[4 * q + 1]);
      pbk.z = f32_to_bf16_rne(vb[4 * q + 2]);
      pbk.w = f32_to_bf16_rne(vb[4 * q + 3]);
      *reinterpret_cast<ushort4*>(&dst[(size_t)rowa * NN + 256 * q + 4 * lane]) = pa;
      *reinterpret_cast<ushort4*>(&dst[(size_t)rowb * NN + 256 * q + 4 * lane]) = pbk;
    }
  } else {
    unsigned short* dst = (chain == 1) ? S1 : S3;
#pragma unroll
    for (int q = 0; q < 4; ++q)
#pragma unroll
      for (int r = 0; r < 4; ++r) {
        const size_t e = 256 * q + 4 * lane + r;
        unsigned int pk = pack2bf(va[4 * q + r], vb[4 * q + r]);
        *reinterpret_cast<unsigned int*>(&dst[e * NN + rowa]) = pk;  // rowa even
      }
  }
}

// -------------------- generic 1024^3 bf16 compose: D[m][n] = sum_k X[m][k]*W[n][k] --------------------
#define BM 128
#define BN 128
#define BK 32
#define LDK 40

__device__ __forceinline__ void compose_body(
    const unsigned short* __restrict__ Xb, const unsigned short* __restrict__ Wb,
    unsigned short* __restrict__ Op, const float* __restrict__ sig, int b) {
  __shared__ unsigned short As[BM * LDK];
  __shared__ unsigned short Bs[BN * LDK];
  const int tid = threadIdx.x;
  const int lane = tid & 63, wave = tid >> 6;
  const int bm = b & 7, bn = b >> 3;
  const int m0 = bm * BM, n0 = bn * BN;
  const int wm = wave & 1, wn = wave >> 1;

  const int srow = tid >> 1;
  const int scol = (tid & 1) << 4;
  const unsigned short* aptr = Xb + (size_t)(m0 + srow) * NN + scol;
  const unsigned short* bptr = Wb + (size_t)(n0 + srow) * NN + scol;

  f32x4 acc[4][4];
#pragma unroll
  for (int a = 0; a < 4; ++a)
#pragma unroll
    for (int bb = 0; bb < 4; ++bb) acc[a][bb] = 0.f;

  uint4 ra0 = *reinterpret_cast<const uint4*>(aptr + 0);
  uint4 ra1 = *reinterpret_cast<const uint4*>(aptr + 8);
  uint4 rb0 = *reinterpret_cast<const uint4*>(bptr + 0);
  uint4 rb1 = *reinterpret_cast<const uint4*>(bptr + 8);

  const int arow0 = wm * 64;
  const int brow0 = wn * 64;
  const int fr = lane & 15;
  const int kb = (lane >> 4) << 3;

#pragma unroll 1
  for (int kt = 0; kt < NN / BK; ++kt) {
    __syncthreads();
    *reinterpret_cast<uint4*>(&As[srow * LDK + scol]) = ra0;
    *reinterpret_cast<uint4*>(&As[srow * LDK + scol + 8]) = ra1;
    *reinterpret_cast<uint4*>(&Bs[srow * LDK + scol]) = rb0;
    *reinterpret_cast<uint4*>(&Bs[srow * LDK + scol + 8]) = rb1;
    __syncthreads();
    if (kt + 1 < NN / BK) {
      const unsigned short* ap = aptr + (kt + 1) * BK;
      const unsigned short* bp = bptr + (kt + 1) * BK;
      ra0 = *reinterpret_cast<const uint4*>(ap + 0);
      ra1 = *reinterpret_cast<const uint4*>(ap + 8);
      rb0 = *reinterpret_cast<const uint4*>(bp + 0);
      rb1 = *reinterpret_cast<const uint4*>(bp + 8);
    }
    short8 af[4], bf[4];
#pragma unroll
    for (int tr = 0; tr < 4; ++tr)
      af[tr] = *reinterpret_cast<const short8*>(&As[(arow0 + tr * 16 + fr) * LDK + kb]);
#pragma unroll
    for (int tc = 0; tc < 4; ++tc)
      bf[tc] = *reinterpret_cast<const short8*>(&Bs[(brow0 + tc * 16 + fr) * LDK + kb]);
#pragma unroll
    for (int tr = 0; tr < 4; ++tr)
#pragma unroll
      for (int tc = 0; tc < 4; ++tc)
        acc[tr][tc] = __builtin_amdgcn_mfma_f32_16x16x32_bf16(af[tr], bf[tc], acc[tr][tc], 0, 0, 0);
  }

  const int rq = (lane >> 4) << 2;
#pragma unroll
  for (int tc = 0; tc < 4; ++tc) {
    const int gc = n0 + brow0 + tc * 16 + fr;
    const float s = sig ? sig[gc] : 1.0f;
#pragma unroll
    for (int tr = 0; tr < 4; ++tr) {
      const int gr = m0 + arow0 + tr * 16 + rq;
#pragma unroll
      for (int q = 0; q < 4; ++q) {
        Op[(size_t)(gr + q) * NN + gc] = f32_to_bf16_rne(acc[tr][tc][q] * s);
      }
    }
  }
}

// #1 and #2 fused (independent): 128 blocks.
__global__ __launch_bounds__(256) void composeAB_kernel(
    const unsigned short* __restrict__ Alo, const unsigned short* __restrict__ S1,
    const unsigned short* __restrict__ Bhi, const unsigned short* __restrict__ S3,
    const float* __restrict__ sigmas,
    unsigned short* __restrict__ Asig, unsigned short* __restrict__ Bt2) {
  const int b = blockIdx.x;
  if (b < 64) {
    // Asig[k][j] = (sum_m Alo[k][m] * Ahi[m][j]) * sigma_j ; S1[j][m] = Ahi[m][j]
    compose_body(Alo, S1, Asig, sigmas, b);
  } else {
    // Bt2[n][j] = sum_m Blo[m][n] * Bhi[j][m] = B[j][n] ; S3[n][m] = Blo[m][n]
    compose_body(S3, Bhi, Bt2, nullptr, b - 64);
  }
}

// #3: Mt[n][k] = sum_j Bt2[n][j] * Asig[k][j]. 64 blocks.
__global__ __launch_bounds__(256) void composeMt_kernel(
    const unsigned short* __restrict__ Bt2, const unsigned short* __restrict__ Asig,
    unsigned short* __restrict__ Mt) {
  compose_body(Bt2, Asig, Mt, nullptr, blockIdx.x);
}

// -------------------- GEMM: out = x @ M + bias (X f32 -> bf16 on the fly) ----
__global__ __launch_bounds__(256) void gemm_kernel(
    const float* __restrict__ X, const unsigned short* __restrict__ Mt,
    const float* __restrict__ bias, float* __restrict__ Out) {
  __shared__ unsigned short As[BM * LDK];
  __shared__ unsigned short Bs[BN * LDK];
  const int tid = threadIdx.x;
  const int lane = tid & 63, wave = tid >> 6;
  const int bm = blockIdx.x & 127;
  const int bn = blockIdx.x >> 7;
  const int m0 = bm * BM, n0 = bn * BN;
  const int wm = wave & 1, wn = wave >> 1;

  const int srow = tid >> 1;
  const int scol = (tid & 1) << 4;
  const float* aptr = X + (size_t)(m0 + srow) * NN + scol;
  const unsigned short* bptr = Mt + (size_t)(n0 + srow) * NN + scol;

  f32x4 acc[4][4];
#pragma unroll
  for (int a = 0; a < 4; ++a)
#pragma unroll
    for (int b = 0; b < 4; ++b) acc[a][b] = 0.f;

  float4 ra0 = *reinterpret_cast<const float4*>(aptr + 0);
  float4 ra1 = *reinterpret_cast<const float4*>(aptr + 4);
  float4 ra2 = *reinterpret_cast<const float4*>(aptr + 8);
  float4 ra3 = *reinterpret_cast<const float4*>(aptr + 12);
  uint4 rb0 = *reinterpret_cast<const uint4*>(bptr + 0);
  uint4 rb1 = *reinterpret_cast<const uint4*>(bptr + 8);

  const int arow0 = wm * 64;
  const int brow0 = wn * 64;
  const int fr = lane & 15;
  const int kb = (lane >> 4) << 3;

#pragma unroll 1
  for (int kt = 0; kt < NN / BK; ++kt) {
    __syncthreads();
    uint4 w0, w1;
    w0.x = pack2bf(ra0.x, ra0.y); w0.y = pack2bf(ra0.z, ra0.w);
    w0.z = pack2bf(ra1.x, ra1.y); w0.w = pack2bf(ra1.z, ra1.w);
    w1.x = pack2bf(ra2.x, ra2.y); w1.y = pack2bf(ra2.z, ra2.w);
    w1.z = pack2bf(ra3.x, ra3.y); w1.w = pack2bf(ra3.z, ra3.w);
    *reinterpret_cast<uint4*>(&As[srow * LDK + scol]) = w0;
    *reinterpret_cast<uint4*>(&As[srow * LDK + scol + 8]) = w1;
    *reinterpret_cast<uint4*>(&Bs[srow * LDK + scol]) = rb0;
    *reinterpret_cast<uint4*>(&Bs[srow * LDK + scol + 8]) = rb1;
    __syncthreads();
    if (kt + 1 < NN / BK) {
      const float* ap = aptr + (kt + 1) * BK;
      const unsigned short* bp = bptr + (kt + 1) * BK;
      ra0 = *reinterpret_cast<const float4*>(ap + 0);
      ra1 = *reinterpret_cast<const float4*>(ap + 4);
      ra2 = *reinterpret_cast<const float4*>(ap + 8);
      ra3 = *reinterpret_cast<const float4*>(ap + 12);
      rb0 = *reinterpret_cast<const uint4*>(bp + 0);
      rb1 = *reinterpret_cast<const uint4*>(bp + 8);
    }
    short8 af[4], bf[4];
#pragma unroll
    for (int tr = 0; tr < 4; ++tr)
      af[tr] = *reinterpret_cast<const short8*>(&As[(arow0 + tr * 16 + fr) * LDK + kb]);
#pragma unroll
    for (int tc = 0; tc < 4; ++tc)
      bf[tc] = *reinterpret_cast<const short8*>(&Bs[(brow0 + tc * 16 + fr) * LDK + kb]);
#pragma unroll
    for (int tr = 0; tr < 4; ++tr)
#pragma unroll
      for (int tc = 0; tc < 4; ++tc)
        acc[tr][tc] = __builtin_amdgcn_mfma_f32_16x16x32_bf16(af[tr], bf[tc], acc[tr][tc], 0, 0, 0);
  }

  const int rq = (lane >> 4) << 2;
#pragma unroll
  for (int tc = 0; tc < 4; ++tc) {
    const int gc = n0 + brow0 + tc * 16 + fr;
    const float bv = bias[gc];
#pragma unroll
    for (int tr = 0; tr < 4; ++tr) {
      const int gr = m0 + arow0 + tr * 16 + rq;
#pragma unroll
      for (int q = 0; q < 4; ++q) {
        Out[(size_t)(gr + q) * NN + gc] = acc[tr][tc][q] + bv;
      }
    }
  }
}

extern "C" void kernel_launch(void* const* d_in, const int* in_sizes, int n_in,
                              void* d_out, int out_size, void* d_ws, size_t ws_size,
                              hipStream_t stream) {
  const float* x = (const float*)d_in[0];
  const float* U = (const float*)d_in[1];
  const float* V = (const float*)d_in[2];
  const float* p = (const float*)d_in[3];
  const float* bias = (const float*)d_in[4];
  float* out = (float*)d_out;

  char* ws = (char*)d_ws;
  float* tau_u = (float*)(ws);
  float* tau_v = (float*)(ws + 4096);
  float* sigmas = (float*)(ws + 8192);
  float* T8all = (float*)(ws + 16384);                 // 64 KB
  unsigned short* Mt = (unsigned short*)(ws + 81920);  // 2 MB (must survive until gemm)

  // Large temporaries live in d_out (64 MB) and are fully consumed before gemm
  // overwrites d_out. 6 matrices x 1M bf16 elements = 12 MB.
  unsigned short* sc = (unsigned short*)d_out;
  const size_t ME = (size_t)NN * NN;
  unsigned short* Alo  = sc + 0 * ME;  // row-major  Alo[k][m]
  unsigned short* S1   = sc + 1 * ME;  // transposed S1[j][m] = Ahi[m][j]
  unsigned short* Bhi  = sc + 2 * ME;  // row-major  Bhi[j][m]
  unsigned short* S3   = sc + 3 * ME;  // transposed S3[n][m] = Blo[m][n]
  unsigned short* Asig = sc + 4 * ME;  // Asig[k][j] = A[k][j]*sigma_j
  unsigned short* Bt2  = sc + 5 * ME;  // Bt2[n][j]  = B[j][n]

  prep_kernel<<<516, 256, 0, stream>>>(U, V, p, tau_u, tau_v, sigmas);
  gram_t8_kernel<<<256, 64, 0, stream>>>(U, V, tau_u, tau_v, T8all);
  build4_kernel<<<512, 256, 0, stream>>>(U, V, T8all, Alo, S1, Bhi, S3);
  composeAB_kernel<<<128, 256, 0, stream>>>(Alo, S1, Bhi, S3, sigmas, Asig, Bt2);
  composeMt_kernel<<<64, 256, 0, stream>>>(Bt2, Asig, Mt);
  gemm_kernel<<<1024, 256, 0, stream>>>(x, Mt, bias, out);
}

// Round 7
// 455.229 us; speedup vs baseline: 1.4415x; 1.0871x over previous
//
#include <hip/hip_runtime.h>
#include <stdint.h>

typedef __attribute__((ext_vector_type(8))) short short8;
typedef __attribute__((ext_vector_type(4))) float f32x4;

#define NN 1024
#define NBATCH 16384

__device__ __forceinline__ unsigned short f32_to_bf16_rne(float f) {
  unsigned int u = __float_as_uint(f);
  unsigned int r = (u + 0x7fffu + ((u >> 16) & 1u)) >> 16;
  return (unsigned short)r;
}

__device__ __forceinline__ unsigned int pack2bf(float lo, float hi) {
  return (unsigned int)f32_to_bf16_rne(lo) | ((unsigned int)f32_to_bf16_rne(hi) << 16);
}

// 64-lane all-reduce sum: 4 DPP (VALU) stages + ds_swizzle xor16 + shfl xor32.
__device__ __forceinline__ float allsum64(float x) {
  x += __int_as_float(__builtin_amdgcn_update_dpp(0, __float_as_int(x), 0xB1, 0xF, 0xF, true));   // xor1
  x += __int_as_float(__builtin_amdgcn_update_dpp(0, __float_as_int(x), 0x4E, 0xF, 0xF, true));   // xor2
  x += __int_as_float(__builtin_amdgcn_update_dpp(0, __float_as_int(x), 0x141, 0xF, 0xF, true));  // xor4 (row_half_mirror)
  x += __int_as_float(__builtin_amdgcn_update_dpp(0, __float_as_int(x), 0x140, 0xF, 0xF, true));  // xor8 (row_mirror)
  x += __int_as_float(__builtin_amdgcn_ds_swizzle(__float_as_int(x), 0x401F));                    // xor16
  x += __shfl_xor(x, 32);
  return x;
}

// -------------------- prep: tau = 2/(u.u), sigmas --------------------
__global__ __launch_bounds__(256) void prep_kernel(
    const float* __restrict__ U, const float* __restrict__ V,
    const float* __restrict__ p, float* __restrict__ tau_u,
    float* __restrict__ tau_v, float* __restrict__ sigmas) {
  int wave = threadIdx.x >> 6, lane = threadIdx.x & 63;
  int row = blockIdx.x * 4 + wave;
  if (row < 2048) {
    const float* u = (row < NN) ? (U + (size_t)row * NN) : (V + (size_t)(row - NN) * NN);
    float s = 0.f;
#pragma unroll
    for (int t = 0; t < 16; ++t) { float a = u[lane + (t << 6)]; s += a * a; }
    s = allsum64(s);
    if (lane == 0) {
      float tau = 2.0f / s;
      if (row < NN) tau_u[row] = tau;
      else tau_v[row - NN] = tau;
    }
  } else if (row < 2064) {
    int j = ((row - 2048) << 6) + lane;
    float pj = p[j];
    float sg = 1.0f / (1.0f + expf(-pj));
    sigmas[j] = 0.9f * (sg - 0.5f) + 0.55f;  // r=0.45, mean=0.55
  }
}

// -------------------- gram + T8 per block of 8 reflectors --------------------
// blk<128: U bank, rows 8*blk+j (j=0..7). blk>=128: s=blk-128, V bank, rows 1023-8s-j.
__global__ __launch_bounds__(64) void gram_t8_kernel(
    const float* __restrict__ U, const float* __restrict__ V,
    const float* __restrict__ tau_u, const float* __restrict__ tau_v,
    float* __restrict__ T8all) {
  __shared__ float G[64];
  const int blk = blockIdx.x;
  const int lane = threadIdx.x;
  const float* bank;
  int rbase, rsign, st;
  if (blk < 128) { bank = U; rbase = 8 * blk; rsign = 1; st = 8 * blk; }
  else { int s = blk - 128; bank = V; rbase = 1023 - 8 * s; rsign = -1; st = 1016 - 8 * s; }

  if (lane < 28) {
    int j = 1, k = 0, t = lane;
    for (int jj = 1; jj < 8; ++jj) {
      int lo = jj * (jj - 1) / 2, hi = jj * (jj + 1) / 2;
      if (t >= lo && t < hi) { j = jj; k = t - lo; }
    }
    const float* rk = bank + (size_t)(rbase + rsign * k) * NN;
    const float* rj = bank + (size_t)(rbase + rsign * j) * NN;
    float acc = 0.f;
    for (int i = st >> 2; i < 256; ++i) {
      float4 a = *reinterpret_cast<const float4*>(rk + 4 * i);
      float4 b = *reinterpret_cast<const float4*>(rj + 4 * i);
      acc += a.x * b.x + a.y * b.y + a.z * b.z + a.w * b.w;
    }
    G[k * 8 + j] = acc;
  }
  __syncthreads();

  if (lane < 8) {
    float Tr[8];
#pragma unroll
    for (int j = 0; j < 8; ++j) Tr[j] = 0.f;
#pragma unroll
    for (int j = 0; j < 8; ++j) {
      int grow = rbase + rsign * j;
      float tj = (blk < 128) ? tau_u[grow] : tau_v[grow];
      float a = 0.f;
#pragma unroll
      for (int k = 0; k < 8; ++k) {
        if (k < j) a += Tr[k] * G[k * 8 + j];
      }
      Tr[j] = (lane == j) ? tj : (-tj * a);
    }
#pragma unroll
    for (int j = 0; j < 8; ++j) T8all[(size_t)blk * 64 + lane * 8 + j] = Tr[j];
  }
}

// -------------------- build 4 half-chains: 256 blocks x 256 threads, 4 rows/wave ----
// chain 0: Alo = H_u0..H_u511      (asc,  q0 segs {0,1}),  store row-major
// chain 1: Ahi = H_u512..H_u1023   (asc,  q0 segs {2,3}),  store transposed
// chain 2: Bhi = H_v1023..H_v512   (desc, q0 segs {3,2}),  store row-major
// chain 3: Blo = H_v511..H_v0      (desc, q0 segs {1,0}),  store transposed
// Element map: v[r][4q+e] holds element 256q+4*lane+e of row row0+r.
// Block (bid&63) owns 16 rows; wave w owns rows base+4w..base+4w+3.
// R=4 rows/wave amortizes the LDS u-reads (the binding pipe at R=2, see R6 PMC).
// NOTE (R4/R5 lesson): do NOT pass a min-occupancy arg to __launch_bounds__.
__device__ __forceinline__ void stage4(int chain, int step, float* lbuf, float* tbuf,
    const float* __restrict__ U, const float* __restrict__ V,
    const float* __restrict__ T8all, int wave, int lane) {
  if (step >= 64) return;
  int q0, rbase, rsign, t8i;
  const float* bank;
  switch (chain) {
    case 0:  q0 = step >> 5;              bank = U; rbase = 8 * step;        rsign = 1;  t8i = step;       break;
    case 1:  q0 = 2 + (step >> 5);        bank = U; rbase = 512 + 8 * step;  rsign = 1;  t8i = 64 + step;  break;
    case 2:  q0 = (1016 - 8 * step) >> 8; bank = V; rbase = 1023 - 8 * step; rsign = -1; t8i = 128 + step; break;
    default: q0 = (504 - 8 * step) >> 8;  bank = V; rbase = 511 - 8 * step;  rsign = -1; t8i = 192 + step; break;
  }
#pragma unroll
  for (int c = 0; c < 8; ++c) {
    const int chunk = (wave << 3) + c;   // 4 waves x 8 chunks = 8 slots x 4 quarters
    const int slot = chunk >> 2, q = chunk & 3;
    if (q < q0) continue;
    const int grow = rbase + rsign * slot;
    const float* gsrc = bank + (size_t)grow * NN + q * 256 + lane * 4;
    float* ldst = lbuf + slot * NN + q * 256;
    __builtin_amdgcn_global_load_lds(
        (const __attribute__((address_space(1))) void*)gsrc,
        (__attribute__((address_space(3))) void*)ldst, 16, 0, 0);
  }
  if (wave == 0 && lane < 16) {
    float4 t = *reinterpret_cast<const float4*>(T8all + (size_t)t8i * 64 + lane * 4);
    *reinterpret_cast<float4*>(tbuf + lane * 4) = t;
  }
}

// Two-pass WY-8 application on FOUR rows per wave. One LDS u-read feeds 4 rows'
// dots (pass 1) and 4 rows' updates (pass 2). w computed in-place in c
// (descending j) to save 32 VGPRs. All array indices compile-time (rule #20).
template <int Q0>
__device__ __forceinline__ void apply_block4(const float* __restrict__ ub,
    const float* __restrict__ tb, float v[4][16], int lane) {
  float c[4][8];
  // pass 1: dots for 4 rows
#pragma unroll
  for (int j = 0; j < 8; ++j) {
    float a0 = 0.f, a1 = 0.f, a2 = 0.f, a3 = 0.f;
#pragma unroll
    for (int q = Q0; q < 4; ++q) {
      const float4 uu = *reinterpret_cast<const float4*>(&ub[j * NN + q * 256 + lane * 4]);
      a0 += uu.x * v[0][4 * q + 0] + uu.y * v[0][4 * q + 1] +
            uu.z * v[0][4 * q + 2] + uu.w * v[0][4 * q + 3];
      a1 += uu.x * v[1][4 * q + 0] + uu.y * v[1][4 * q + 1] +
            uu.z * v[1][4 * q + 2] + uu.w * v[1][4 * q + 3];
      a2 += uu.x * v[2][4 * q + 0] + uu.y * v[2][4 * q + 1] +
            uu.z * v[2][4 * q + 2] + uu.w * v[2][4 * q + 3];
      a3 += uu.x * v[3][4 * q + 0] + uu.y * v[3][4 * q + 1] +
            uu.z * v[3][4 * q + 2] + uu.w * v[3][4 * q + 3];
    }
    c[0][j] = a0; c[1][j] = a1; c[2][j] = a2; c[3][j] = a3;
  }
#pragma unroll
  for (int r = 0; r < 4; ++r)
#pragma unroll
    for (int j = 0; j < 8; ++j) c[r][j] = allsum64(c[r][j]);
  // w = c * T (T upper-tri), in place descending j: c[r][k<j] still original.
#pragma unroll
  for (int j = 7; j >= 0; --j) {
#pragma unroll
    for (int r = 0; r < 4; ++r) {
      float acc = 0.f;
#pragma unroll
      for (int k = 0; k < 8; ++k) {
        if (k <= j) acc += c[r][k] * tb[k * 8 + j];
      }
      c[r][j] = acc;
    }
  }
  // pass 2: update 4 rows (re-read u from LDS; q outer keeps v register-resident)
#pragma unroll
  for (int q = Q0; q < 4; ++q) {
#pragma unroll
    for (int j = 0; j < 8; ++j) {
      const float4 uu = *reinterpret_cast<const float4*>(&ub[j * NN + q * 256 + lane * 4]);
#pragma unroll
      for (int r = 0; r < 4; ++r) {
        v[r][4 * q + 0] -= c[r][j] * uu.x;
        v[r][4 * q + 1] -= c[r][j] * uu.y;
        v[r][4 * q + 2] -= c[r][j] * uu.z;
        v[r][4 * q + 3] -= c[r][j] * uu.w;
      }
    }
  }
}

__global__ __launch_bounds__(256) void build4_kernel(
    const float* __restrict__ U, const float* __restrict__ V,
    const float* __restrict__ T8all,
    unsigned short* __restrict__ Alo, unsigned short* __restrict__ S1,
    unsigned short* __restrict__ Bhi, unsigned short* __restrict__ S3) {
  __shared__ float ubuf[2][8 * NN];
  __shared__ float tbuf[2][64];
  const int tid = threadIdx.x;
  const int wave = tid >> 6, lane = tid & 63;
  const int chain = blockIdx.x >> 6;
  const int row0 = ((blockIdx.x & 63) << 4) + (wave << 2);

  float v[4][16];
#pragma unroll
  for (int q = 0; q < 4; ++q)
#pragma unroll
    for (int e = 0; e < 4; ++e) {
      const int el = 256 * q + 4 * lane + e;
#pragma unroll
      for (int r = 0; r < 4; ++r) v[r][4 * q + e] = (el == row0 + r) ? 1.0f : 0.0f;
    }

  stage4(chain, 0, ubuf[0], tbuf[0], U, V, T8all, wave, lane);
  int pb = 0;

#define SEG(Q0C, BASE)                                                            \
  for (int s = 0; s < 32; ++s) {                                                  \
    const int step = (BASE) + s;                                                  \
    __syncthreads(); /* vmcnt drained: staged buf ready, prev buf consumed */     \
    stage4(chain, step + 1, ubuf[pb ^ 1], tbuf[pb ^ 1], U, V, T8all, wave, lane); \
    apply_block4<Q0C>(ubuf[pb], tbuf[pb], v, lane);                               \
    pb ^= 1;                                                                      \
  }

  if (chain == 0)      { SEG(0, 0) SEG(1, 32) }
  else if (chain == 1) { SEG(2, 0) SEG(3, 32) }
  else if (chain == 2) { SEG(3, 0) SEG(2, 32) }
  else                 { SEG(1, 0) SEG(0, 32) }
#undef SEG

  if (chain == 0 || chain == 2) {
    unsigned short* dst = (chain == 0) ? Alo : Bhi;
#pragma unroll
    for (int r = 0; r < 4; ++r) {
#pragma unroll
      for (int q = 0; q < 4; ++q) {
        ushort4 pk;
        pk.x = f32_to_bf16_rne(v[r][4 * q + 0]);
        pk.y = f32_to_bf16_rne(v[r][4 * q + 1]);
        pk.z = f32_to_bf16_rne(v[r][4 * q + 2]);
        pk.w = f32_to_bf16_rne(v[r][4 * q + 3]);
        *reinterpret_cast<ushort4*>(&dst[(size_t)(row0 + r) * NN + 256 * q + 4 * lane]) = pk;
      }
    }
  } else {
    unsigned short* dst = (chain == 1) ? S1 : S3;
#pragma unroll
    for (int q = 0; q < 4; ++q)
#pragma unroll
      for (int e = 0; e < 4; ++e) {
        const size_t el = 256 * q + 4 * lane + e;
        ushort4 pk;
        pk.x = f32_to_bf16_rne(v[0][4 * q + e]);
        pk.y = f32_to_bf16_rne(v[1][4 * q + e]);
        pk.z = f32_to_bf16_rne(v[2][4 * q + e]);
        pk.w = f32_to_bf16_rne(v[3][4 * q + e]);
        *reinterpret_cast<ushort4*>(&dst[el * NN + row0]) = pk;  // row0 % 4 == 0
      }
  }
}

// -------------------- generic 1024^3 bf16 compose: D[m][n] = sum_k X[m][k]*W[n][k] --------------------
#define BM 128
#define BN 128
#define BK 32
#define LDK 40

__device__ __forceinline__ void compose_body(
    const unsigned short* __restrict__ Xb, const unsigned short* __restrict__ Wb,
    unsigned short* __restrict__ Op, const float* __restrict__ sig, int b) {
  __shared__ unsigned short As[BM * LDK];
  __shared__ unsigned short Bs[BN * LDK];
  const int tid = threadIdx.x;
  const int lane = tid & 63, wave = tid >> 6;
  const int bm = b & 7, bn = b >> 3;
  const int m0 = bm * BM, n0 = bn * BN;
  const int wm = wave & 1, wn = wave >> 1;

  const int srow = tid >> 1;
  const int scol = (tid & 1) << 4;
  const unsigned short* aptr = Xb + (size_t)(m0 + srow) * NN + scol;
  const unsigned short* bptr = Wb + (size_t)(n0 + srow) * NN + scol;

  f32x4 acc[4][4];
#pragma unroll
  for (int a = 0; a < 4; ++a)
#pragma unroll
    for (int bb = 0; bb < 4; ++bb) acc[a][bb] = 0.f;

  uint4 ra0 = *reinterpret_cast<const uint4*>(aptr + 0);
  uint4 ra1 = *reinterpret_cast<const uint4*>(aptr + 8);
  uint4 rb0 = *reinterpret_cast<const uint4*>(bptr + 0);
  uint4 rb1 = *reinterpret_cast<const uint4*>(bptr + 8);

  const int arow0 = wm * 64;
  const int brow0 = wn * 64;
  const int fr = lane & 15;
  const int kb = (lane >> 4) << 3;

#pragma unroll 1
  for (int kt = 0; kt < NN / BK; ++kt) {
    __syncthreads();
    *reinterpret_cast<uint4*>(&As[srow * LDK + scol]) = ra0;
    *reinterpret_cast<uint4*>(&As[srow * LDK + scol + 8]) = ra1;
    *reinterpret_cast<uint4*>(&Bs[srow * LDK + scol]) = rb0;
    *reinterpret_cast<uint4*>(&Bs[srow * LDK + scol + 8]) = rb1;
    __syncthreads();
    if (kt + 1 < NN / BK) {
      const unsigned short* ap = aptr + (kt + 1) * BK;
      const unsigned short* bp = bptr + (kt + 1) * BK;
      ra0 = *reinterpret_cast<const uint4*>(ap + 0);
      ra1 = *reinterpret_cast<const uint4*>(ap + 8);
      rb0 = *reinterpret_cast<const uint4*>(bp + 0);
      rb1 = *reinterpret_cast<const uint4*>(bp + 8);
    }
    short8 af[4], bf[4];
#pragma unroll
    for (int tr = 0; tr < 4; ++tr)
      af[tr] = *reinterpret_cast<const short8*>(&As[(arow0 + tr * 16 + fr) * LDK + kb]);
#pragma unroll
    for (int tc = 0; tc < 4; ++tc)
      bf[tc] = *reinterpret_cast<const short8*>(&Bs[(brow0 + tc * 16 + fr) * LDK + kb]);
#pragma unroll
    for (int tr = 0; tr < 4; ++tr)
#pragma unroll
      for (int tc = 0; tc < 4; ++tc)
        acc[tr][tc] = __builtin_amdgcn_mfma_f32_16x16x32_bf16(af[tr], bf[tc], acc[tr][tc], 0, 0, 0);
  }

  const int rq = (lane >> 4) << 2;
#pragma unroll
  for (int tc = 0; tc < 4; ++tc) {
    const int gc = n0 + brow0 + tc * 16 + fr;
    const float s = sig ? sig[gc] : 1.0f;
#pragma unroll
    for (int tr = 0; tr < 4; ++tr) {
      const int gr = m0 + arow0 + tr * 16 + rq;
#pragma unroll
      for (int q = 0; q < 4; ++q) {
        Op[(size_t)(gr + q) * NN + gc] = f32_to_bf16_rne(acc[tr][tc][q] * s);
      }
    }
  }
}

// #1 and #2 fused (independent): 128 blocks.
__global__ __launch_bounds__(256) void composeAB_kernel(
    const unsigned short* __restrict__ Alo, const unsigned short* __restrict__ S1,
    const unsigned short* __restrict__ Bhi, const unsigned short* __restrict__ S3,
    const float* __restrict__ sigmas,
    unsigned short* __restrict__ Asig, unsigned short* __restrict__ Bt2) {
  const int b = blockIdx.x;
  if (b < 64) {
    // Asig[k][j] = (sum_m Alo[k][m] * Ahi[m][j]) * sigma_j ; S1[j][m] = Ahi[m][j]
    compose_body(Alo, S1, Asig, sigmas, b);
  } else {
    // Bt2[n][j] = sum_m Blo[m][n] * Bhi[j][m] = B[j][n] ; S3[n][m] = Blo[m][n]
    compose_body(S3, Bhi, Bt2, nullptr, b - 64);
  }
}

// #3: Mt[n][k] = sum_j Bt2[n][j] * Asig[k][j]. 64 blocks.
__global__ __launch_bounds__(256) void composeMt_kernel(
    const unsigned short* __restrict__ Bt2, const unsigned short* __restrict__ Asig,
    unsigned short* __restrict__ Mt) {
  compose_body(Bt2, Asig, Mt, nullptr, blockIdx.x);
}

// -------------------- GEMM: out = x @ M + bias (X f32 -> bf16 on the fly) ----
__global__ __launch_bounds__(256) void gemm_kernel(
    const float* __restrict__ X, const unsigned short* __restrict__ Mt,
    const float* __restrict__ bias, float* __restrict__ Out) {
  __shared__ unsigned short As[BM * LDK];
  __shared__ unsigned short Bs[BN * LDK];
  const int tid = threadIdx.x;
  const int lane = tid & 63, wave = tid >> 6;
  const int bm = blockIdx.x & 127;
  const int bn = blockIdx.x >> 7;
  const int m0 = bm * BM, n0 = bn * BN;
  const int wm = wave & 1, wn = wave >> 1;

  const int srow = tid >> 1;
  const int scol = (tid & 1) << 4;
  const float* aptr = X + (size_t)(m0 + srow) * NN + scol;
  const unsigned short* bptr = Mt + (size_t)(n0 + srow) * NN + scol;

  f32x4 acc[4][4];
#pragma unroll
  for (int a = 0; a < 4; ++a)
#pragma unroll
    for (int b = 0; b < 4; ++b) acc[a][b] = 0.f;

  float4 ra0 = *reinterpret_cast<const float4*>(aptr + 0);
  float4 ra1 = *reinterpret_cast<const float4*>(aptr + 4);
  float4 ra2 = *reinterpret_cast<const float4*>(aptr + 8);
  float4 ra3 = *reinterpret_cast<const float4*>(aptr + 12);
  uint4 rb0 = *reinterpret_cast<const uint4*>(bptr + 0);
  uint4 rb1 = *reinterpret_cast<const uint4*>(bptr + 8);

  const int arow0 = wm * 64;
  const int brow0 = wn * 64;
  const int fr = lane & 15;
  const int kb = (lane >> 4) << 3;

#pragma unroll 1
  for (int kt = 0; kt < NN / BK; ++kt) {
    __syncthreads();
    uint4 w0, w1;
    w0.x = pack2bf(ra0.x, ra0.y); w0.y = pack2bf(ra0.z, ra0.w);
    w0.z = pack2bf(ra1.x, ra1.y); w0.w = pack2bf(ra1.z, ra1.w);
    w1.x = pack2bf(ra2.x, ra2.y); w1.y = pack2bf(ra2.z, ra2.w);
    w1.z = pack2bf(ra3.x, ra3.y); w1.w = pack2bf(ra3.z, ra3.w);
    *reinterpret_cast<uint4*>(&As[srow * LDK + scol]) = w0;
    *reinterpret_cast<uint4*>(&As[srow * LDK + scol + 8]) = w1;
    *reinterpret_cast<uint4*>(&Bs[srow * LDK + scol]) = rb0;
    *reinterpret_cast<uint4*>(&Bs[srow * LDK + scol + 8]) = rb1;
    __syncthreads();
    if (kt + 1 < NN / BK) {
      const float* ap = aptr + (kt + 1) * BK;
      const unsigned short* bp = bptr + (kt + 1) * BK;
      ra0 = *reinterpret_cast<const float4*>(ap + 0);
      ra1 = *reinterpret_cast<const float4*>(ap + 4);
      ra2 = *reinterpret_cast<const float4*>(ap + 8);
      ra3 = *reinterpret_cast<const float4*>(ap + 12);
      rb0 = *reinterpret_cast<const uint4*>(bp + 0);
      rb1 = *reinterpret_cast<const uint4*>(bp + 8);
    }
    short8 af[4], bf[4];
#pragma unroll
    for (int tr = 0; tr < 4; ++tr)
      af[tr] = *reinterpret_cast<const short8*>(&As[(arow0 + tr * 16 + fr) * LDK + kb]);
#pragma unroll
    for (int tc = 0; tc < 4; ++tc)
      bf[tc] = *reinterpret_cast<const short8*>(&Bs[(brow0 + tc * 16 + fr) * LDK + kb]);
#pragma unroll
    for (int tr = 0; tr < 4; ++tr)
#pragma unroll
      for (int tc = 0; tc < 4; ++tc)
        acc[tr][tc] = __builtin_amdgcn_mfma_f32_16x16x32_bf16(af[tr], bf[tc], acc[tr][tc], 0, 0, 0);
  }

  const int rq = (lane >> 4) << 2;
#pragma unroll
  for (int tc = 0; tc < 4; ++tc) {
    const int gc = n0 + brow0 + tc * 16 + fr;
    const float bv = bias[gc];
#pragma unroll
    for (int tr = 0; tr < 4; ++tr) {
      const int gr = m0 + arow0 + tr * 16 + rq;
#pragma unroll
      for (int q = 0; q < 4; ++q) {
        Out[(size_t)(gr + q) * NN + gc] = acc[tr][tc][q] + bv;
      }
    }
  }
}

extern "C" void kernel_launch(void* const* d_in, const int* in_sizes, int n_in,
                              void* d_out, int out_size, void* d_ws, size_t ws_size,
                              hipStream_t stream) {
  const float* x = (const float*)d_in[0];
  const float* U = (const float*)d_in[1];
  const float* V = (const float*)d_in[2];
  const float* p = (const float*)d_in[3];
  const float* bias = (const float*)d_in[4];
  float* out = (float*)d_out;

  char* ws = (char*)d_ws;
  float* tau_u = (float*)(ws);
  float* tau_v = (float*)(ws + 4096);
  float* sigmas = (float*)(ws + 8192);
  float* T8all = (float*)(ws + 16384);                 // 64 KB
  unsigned short* Mt = (unsigned short*)(ws + 81920);  // 2 MB (must survive until gemm)

  // Large temporaries live in d_out (64 MB) and are fully consumed before gemm
  // overwrites d_out. 6 matrices x 1M bf16 elements = 12 MB.
  unsigned short* sc = (unsigned short*)d_out;
  const size_t ME = (size_t)NN * NN;
  unsigned short* Alo  = sc + 0 * ME;  // row-major  Alo[k][m]
  unsigned short* S1   = sc + 1 * ME;  // transposed S1[j][m] = Ahi[m][j]
  unsigned short* Bhi  = sc + 2 * ME;  // row-major  Bhi[j][m]
  unsigned short* S3   = sc + 3 * ME;  // transposed S3[n][m] = Blo[m][n]
  unsigned short* Asig = sc + 4 * ME;  // Asig[k][j] = A[k][j]*sigma_j
  unsigned short* Bt2  = sc + 5 * ME;  // Bt2[n][j]  = B[j][n]

  prep_kernel<<<516, 256, 0, stream>>>(U, V, p, tau_u, tau_v, sigmas);
  gram_t8_kernel<<<256, 64, 0, stream>>>(U, V, tau_u, tau_v, T8all);
  build4_kernel<<<256, 256, 0, stream>>>(U, V, T8all, Alo, S1, Bhi, S3);
  composeAB_kernel<<<128, 256, 0, stream>>>(Alo, S1, Bhi, S3, sigmas, Asig, Bt2);
  composeMt_kernel<<<64, 256, 0, stream>>>(Bt2, Asig, Mt);
  gemm_kernel<<<1024, 256, 0, stream>>>(x, Mt, bias, out);
}

// Round 8
// 424.028 us; speedup vs baseline: 1.5476x; 1.0736x over previous
//
#include <hip/hip_runtime.h>
#include <stdint.h>

typedef __attribute__((ext_vector_type(8))) short short8;
typedef __attribute__((ext_vector_type(4))) float f32x4;

#define NN 1024
#define NBATCH 16384

__device__ __forceinline__ unsigned short f32_to_bf16_rne(float f) {
  unsigned int u = __float_as_uint(f);
  unsigned int r = (u + 0x7fffu + ((u >> 16) & 1u)) >> 16;
  return (unsigned short)r;
}

__device__ __forceinline__ unsigned int pack2bf(float lo, float hi) {
  return (unsigned int)f32_to_bf16_rne(lo) | ((unsigned int)f32_to_bf16_rne(hi) << 16);
}

// 64-lane all-reduce sum: 4 DPP (VALU) stages + ds_swizzle xor16 + shfl xor32.
__device__ __forceinline__ float allsum64(float x) {
  x += __int_as_float(__builtin_amdgcn_update_dpp(0, __float_as_int(x), 0xB1, 0xF, 0xF, true));   // xor1
  x += __int_as_float(__builtin_amdgcn_update_dpp(0, __float_as_int(x), 0x4E, 0xF, 0xF, true));   // xor2
  x += __int_as_float(__builtin_amdgcn_update_dpp(0, __float_as_int(x), 0x141, 0xF, 0xF, true));  // xor4 (row_half_mirror)
  x += __int_as_float(__builtin_amdgcn_update_dpp(0, __float_as_int(x), 0x140, 0xF, 0xF, true));  // xor8 (row_mirror)
  x += __int_as_float(__builtin_amdgcn_ds_swizzle(__float_as_int(x), 0x401F));                    // xor16
  x += __shfl_xor(x, 32);
  return x;
}

// -------------------- prep: tau = 2/(u.u), sigmas --------------------
__global__ __launch_bounds__(256) void prep_kernel(
    const float* __restrict__ U, const float* __restrict__ V,
    const float* __restrict__ p, float* __restrict__ tau_u,
    float* __restrict__ tau_v, float* __restrict__ sigmas) {
  int wave = threadIdx.x >> 6, lane = threadIdx.x & 63;
  int row = blockIdx.x * 4 + wave;
  if (row < 2048) {
    const float* u = (row < NN) ? (U + (size_t)row * NN) : (V + (size_t)(row - NN) * NN);
    float s = 0.f;
#pragma unroll
    for (int t = 0; t < 16; ++t) { float a = u[lane + (t << 6)]; s += a * a; }
    s = allsum64(s);
    if (lane == 0) {
      float tau = 2.0f / s;
      if (row < NN) tau_u[row] = tau;
      else tau_v[row - NN] = tau;
    }
  } else if (row < 2064) {
    int j = ((row - 2048) << 6) + lane;
    float pj = p[j];
    float sg = 1.0f / (1.0f + expf(-pj));
    sigmas[j] = 0.9f * (sg - 0.5f) + 0.55f;  // r=0.45, mean=0.55
  }
}

// -------------------- gram + T8 per block of 8 reflectors --------------------
// blk<128: U bank, rows 8*blk+j (j=0..7). blk>=128: s=blk-128, V bank, rows 1023-8s-j.
__global__ __launch_bounds__(64) void gram_t8_kernel(
    const float* __restrict__ U, const float* __restrict__ V,
    const float* __restrict__ tau_u, const float* __restrict__ tau_v,
    float* __restrict__ T8all) {
  __shared__ float G[64];
  const int blk = blockIdx.x;
  const int lane = threadIdx.x;
  const float* bank;
  int rbase, rsign, st;
  if (blk < 128) { bank = U; rbase = 8 * blk; rsign = 1; st = 8 * blk; }
  else { int s = blk - 128; bank = V; rbase = 1023 - 8 * s; rsign = -1; st = 1016 - 8 * s; }

  if (lane < 28) {
    int j = 1, k = 0, t = lane;
    for (int jj = 1; jj < 8; ++jj) {
      int lo = jj * (jj - 1) / 2, hi = jj * (jj + 1) / 2;
      if (t >= lo && t < hi) { j = jj; k = t - lo; }
    }
    const float* rk = bank + (size_t)(rbase + rsign * k) * NN;
    const float* rj = bank + (size_t)(rbase + rsign * j) * NN;
    float acc = 0.f;
    for (int i = st >> 2; i < 256; ++i) {
      float4 a = *reinterpret_cast<const float4*>(rk + 4 * i);
      float4 b = *reinterpret_cast<const float4*>(rj + 4 * i);
      acc += a.x * b.x + a.y * b.y + a.z * b.z + a.w * b.w;
    }
    G[k * 8 + j] = acc;
  }
  __syncthreads();

  if (lane < 8) {
    float Tr[8];
#pragma unroll
    for (int j = 0; j < 8; ++j) Tr[j] = 0.f;
#pragma unroll
    for (int j = 0; j < 8; ++j) {
      int grow = rbase + rsign * j;
      float tj = (blk < 128) ? tau_u[grow] : tau_v[grow];
      float a = 0.f;
#pragma unroll
      for (int k = 0; k < 8; ++k) {
        if (k < j) a += Tr[k] * G[k * 8 + j];
      }
      Tr[j] = (lane == j) ? tj : (-tj * a);
    }
#pragma unroll
    for (int j = 0; j < 8; ++j) T8all[(size_t)blk * 64 + lane * 8 + j] = Tr[j];
  }
}

// -------------------- build 8 quarter-chains: 512 blocks x 256 threads, 4 rows/wave ----
// Chain order (heavy Q0=0 first for scheduling): c=0:A1, 1:B1, 2:A2, 3:B2,
// 4:A3, 5:B3, 6:A4, 7:B4.  Q0 = c>>1 (constant per chain; quarter-exact skip).
// A_k = H_u(256k)..H_u(256k+255) asc.  B_k = H_v(256k+255)..H_v(256k) desc,
// B = B4*B3*B2*B1.  32 WY-8 steps per chain.
// Store (for compose tree): A1,B2,A3,B4 row-major; B1,A2,B3,A4 transposed.
// Element map: v[r][4q+e] holds element 256q+4lane+e of row row0+r.
__device__ __forceinline__ void stage8(int c, int step, float* lbuf, float* tbuf,
    const float* __restrict__ U, const float* __restrict__ V,
    const float* __restrict__ T8all, int wave, int lane) {
  if (step >= 32) return;
  const int k = c >> 1;
  const int q0 = k;
  int rbase, rsign, t8i;
  const float* bank;
  if ((c & 1) == 0) {  // U side
    bank = U; rbase = 256 * k + 8 * step; rsign = 1; t8i = 32 * k + step;
  } else {             // V side, descending
    int s = (96 - 32 * k) + step;
    bank = V; rbase = 1023 - 8 * s; rsign = -1; t8i = 128 + s;
  }
#pragma unroll
  for (int cc = 0; cc < 8; ++cc) {
    const int chunk = (wave << 3) + cc;  // 4 waves x 8 chunks = 8 slots x 4 quarters
    const int slot = chunk >> 2, q = chunk & 3;
    if (q < q0) continue;
    const int grow = rbase + rsign * slot;
    const float* gsrc = bank + (size_t)grow * NN + q * 256 + lane * 4;
    float* ldst = lbuf + slot * NN + q * 256;
    __builtin_amdgcn_global_load_lds(
        (const __attribute__((address_space(1))) void*)gsrc,
        (__attribute__((address_space(3))) void*)ldst, 16, 0, 0);
  }
  if (wave == 0 && lane < 16) {
    float4 t = *reinterpret_cast<const float4*>(T8all + (size_t)t8i * 64 + lane * 4);
    *reinterpret_cast<float4*>(tbuf + lane * 4) = t;
  }
}

// Two-pass WY-8 application on FOUR rows per wave (R7 structure, constant Q0).
template <int Q0>
__device__ __forceinline__ void apply_block4(const float* __restrict__ ub,
    const float* __restrict__ tb, float v[4][16], int lane) {
  float c[4][8];
#pragma unroll
  for (int j = 0; j < 8; ++j) {
    float a0 = 0.f, a1 = 0.f, a2 = 0.f, a3 = 0.f;
#pragma unroll
    for (int q = Q0; q < 4; ++q) {
      const float4 uu = *reinterpret_cast<const float4*>(&ub[j * NN + q * 256 + lane * 4]);
      a0 += uu.x * v[0][4 * q + 0] + uu.y * v[0][4 * q + 1] +
            uu.z * v[0][4 * q + 2] + uu.w * v[0][4 * q + 3];
      a1 += uu.x * v[1][4 * q + 0] + uu.y * v[1][4 * q + 1] +
            uu.z * v[1][4 * q + 2] + uu.w * v[1][4 * q + 3];
      a2 += uu.x * v[2][4 * q + 0] + uu.y * v[2][4 * q + 1] +
            uu.z * v[2][4 * q + 2] + uu.w * v[2][4 * q + 3];
      a3 += uu.x * v[3][4 * q + 0] + uu.y * v[3][4 * q + 1] +
            uu.z * v[3][4 * q + 2] + uu.w * v[3][4 * q + 3];
    }
    c[0][j] = a0; c[1][j] = a1; c[2][j] = a2; c[3][j] = a3;
  }
#pragma unroll
  for (int r = 0; r < 4; ++r)
#pragma unroll
    for (int j = 0; j < 8; ++j) c[r][j] = allsum64(c[r][j]);
  // w = c * T (T upper-tri), in place descending j: c[r][k<j] still original.
#pragma unroll
  for (int j = 7; j >= 0; --j) {
#pragma unroll
    for (int r = 0; r < 4; ++r) {
      float acc = 0.f;
#pragma unroll
      for (int k = 0; k < 8; ++k) {
        if (k <= j) acc += c[r][k] * tb[k * 8 + j];
      }
      c[r][j] = acc;
    }
  }
#pragma unroll
  for (int q = Q0; q < 4; ++q) {
#pragma unroll
    for (int j = 0; j < 8; ++j) {
      const float4 uu = *reinterpret_cast<const float4*>(&ub[j * NN + q * 256 + lane * 4]);
#pragma unroll
      for (int r = 0; r < 4; ++r) {
        v[r][4 * q + 0] -= c[r][j] * uu.x;
        v[r][4 * q + 1] -= c[r][j] * uu.y;
        v[r][4 * q + 2] -= c[r][j] * uu.z;
        v[r][4 * q + 3] -= c[r][j] * uu.w;
      }
    }
  }
}

__global__ __launch_bounds__(256) void build8_kernel(
    const float* __restrict__ U, const float* __restrict__ V,
    const float* __restrict__ T8all,
    unsigned short* __restrict__ A1, unsigned short* __restrict__ B1t,
    unsigned short* __restrict__ A2t, unsigned short* __restrict__ B2,
    unsigned short* __restrict__ A3, unsigned short* __restrict__ B3t,
    unsigned short* __restrict__ A4t, unsigned short* __restrict__ B4) {
  __shared__ float ubuf[2][8 * NN];
  __shared__ float tbuf[2][64];
  const int tid = threadIdx.x;
  const int wave = tid >> 6, lane = tid & 63;
  const int c = blockIdx.x >> 6;          // 8 chains x 64 blocks
  const int row0 = ((blockIdx.x & 63) << 4) + (wave << 2);

  float v[4][16];
#pragma unroll
  for (int q = 0; q < 4; ++q)
#pragma unroll
    for (int e = 0; e < 4; ++e) {
      const int el = 256 * q + 4 * lane + e;
#pragma unroll
      for (int r = 0; r < 4; ++r) v[r][4 * q + e] = (el == row0 + r) ? 1.0f : 0.0f;
    }

  stage8(c, 0, ubuf[0], tbuf[0], U, V, T8all, wave, lane);
  int pb = 0;

#define CHAIN_LOOP(Q0C)                                                          \
  for (int s = 0; s < 32; ++s) {                                                 \
    __syncthreads(); /* vmcnt drained: staged buf ready, prev buf consumed */    \
    stage8(c, s + 1, ubuf[pb ^ 1], tbuf[pb ^ 1], U, V, T8all, wave, lane);       \
    apply_block4<Q0C>(ubuf[pb], tbuf[pb], v, lane);                              \
    pb ^= 1;                                                                     \
  }
  switch (c >> 1) {
    case 0: CHAIN_LOOP(0) break;
    case 1: CHAIN_LOOP(1) break;
    case 2: CHAIN_LOOP(2) break;
    default: CHAIN_LOOP(3) break;
  }
#undef CHAIN_LOOP

  unsigned short* dst;
  bool rm;
  switch (c) {
    case 0:  dst = A1;  rm = true;  break;
    case 1:  dst = B1t; rm = false; break;
    case 2:  dst = A2t; rm = false; break;
    case 3:  dst = B2;  rm = true;  break;
    case 4:  dst = A3;  rm = true;  break;
    case 5:  dst = B3t; rm = false; break;
    case 6:  dst = A4t; rm = false; break;
    default: dst = B4;  rm = true;  break;
  }
  if (rm) {
#pragma unroll
    for (int r = 0; r < 4; ++r) {
#pragma unroll
      for (int q = 0; q < 4; ++q) {
        ushort4 pk;
        pk.x = f32_to_bf16_rne(v[r][4 * q + 0]);
        pk.y = f32_to_bf16_rne(v[r][4 * q + 1]);
        pk.z = f32_to_bf16_rne(v[r][4 * q + 2]);
        pk.w = f32_to_bf16_rne(v[r][4 * q + 3]);
        *reinterpret_cast<ushort4*>(&dst[(size_t)(row0 + r) * NN + 256 * q + 4 * lane]) = pk;
      }
    }
  } else {
#pragma unroll
    for (int q = 0; q < 4; ++q)
#pragma unroll
      for (int e = 0; e < 4; ++e) {
        const size_t el = 256 * q + 4 * lane + e;
        ushort4 pk;
        pk.x = f32_to_bf16_rne(v[0][4 * q + e]);
        pk.y = f32_to_bf16_rne(v[1][4 * q + e]);
        pk.z = f32_to_bf16_rne(v[2][4 * q + e]);
        pk.w = f32_to_bf16_rne(v[3][4 * q + e]);
        *reinterpret_cast<ushort4*>(&dst[el * NN + row0]) = pk;  // row0 % 4 == 0
      }
  }
}

// -------------------- generic 1024^3 bf16 compose: D[m][n] = sum_k X[m][k]*W[n][k] ----
// tstore: write D transposed (Op[n][m]) via per-lane ushort4 over the 4 m-values.
#define BM 128
#define BN 128
#define BK 32
#define LDK 40

__device__ __forceinline__ void compose_body(
    const unsigned short* __restrict__ Xb, const unsigned short* __restrict__ Wb,
    unsigned short* __restrict__ Op, const float* __restrict__ sig, int b, bool tstore) {
  __shared__ unsigned short As[BM * LDK];
  __shared__ unsigned short Bs[BN * LDK];
  const int tid = threadIdx.x;
  const int lane = tid & 63, wave = tid >> 6;
  const int bm = b & 7, bn = b >> 3;
  const int m0 = bm * BM, n0 = bn * BN;
  const int wm = wave & 1, wn = wave >> 1;

  const int srow = tid >> 1;
  const int scol = (tid & 1) << 4;
  const unsigned short* aptr = Xb + (size_t)(m0 + srow) * NN + scol;
  const unsigned short* bptr = Wb + (size_t)(n0 + srow) * NN + scol;

  f32x4 acc[4][4];
#pragma unroll
  for (int a = 0; a < 4; ++a)
#pragma unroll
    for (int bb = 0; bb < 4; ++bb) acc[a][bb] = 0.f;

  uint4 ra0 = *reinterpret_cast<const uint4*>(aptr + 0);
  uint4 ra1 = *reinterpret_cast<const uint4*>(aptr + 8);
  uint4 rb0 = *reinterpret_cast<const uint4*>(bptr + 0);
  uint4 rb1 = *reinterpret_cast<const uint4*>(bptr + 8);

  const int arow0 = wm * 64;
  const int brow0 = wn * 64;
  const int fr = lane & 15;
  const int kb = (lane >> 4) << 3;

#pragma unroll 1
  for (int kt = 0; kt < NN / BK; ++kt) {
    __syncthreads();
    *reinterpret_cast<uint4*>(&As[srow * LDK + scol]) = ra0;
    *reinterpret_cast<uint4*>(&As[srow * LDK + scol + 8]) = ra1;
    *reinterpret_cast<uint4*>(&Bs[srow * LDK + scol]) = rb0;
    *reinterpret_cast<uint4*>(&Bs[srow * LDK + scol + 8]) = rb1;
    __syncthreads();
    if (kt + 1 < NN / BK) {
      const unsigned short* ap = aptr + (kt + 1) * BK;
      const unsigned short* bp = bptr + (kt + 1) * BK;
      ra0 = *reinterpret_cast<const uint4*>(ap + 0);
      ra1 = *reinterpret_cast<const uint4*>(ap + 8);
      rb0 = *reinterpret_cast<const uint4*>(bp + 0);
      rb1 = *reinterpret_cast<const uint4*>(bp + 8);
    }
    short8 af[4], bf[4];
#pragma unroll
    for (int tr = 0; tr < 4; ++tr)
      af[tr] = *reinterpret_cast<const short8*>(&As[(arow0 + tr * 16 + fr) * LDK + kb]);
#pragma unroll
    for (int tc = 0; tc < 4; ++tc)
      bf[tc] = *reinterpret_cast<const short8*>(&Bs[(brow0 + tc * 16 + fr) * LDK + kb]);
#pragma unroll
    for (int tr = 0; tr < 4; ++tr)
#pragma unroll
      for (int tc = 0; tc < 4; ++tc)
        acc[tr][tc] = __builtin_amdgcn_mfma_f32_16x16x32_bf16(af[tr], bf[tc], acc[tr][tc], 0, 0, 0);
  }

  const int rq = (lane >> 4) << 2;
  if (!tstore) {
#pragma unroll
    for (int tc = 0; tc < 4; ++tc) {
      const int gc = n0 + brow0 + tc * 16 + fr;
      const float s = sig ? sig[gc] : 1.0f;
#pragma unroll
      for (int tr = 0; tr < 4; ++tr) {
        const int gr = m0 + arow0 + tr * 16 + rq;
#pragma unroll
        for (int q = 0; q < 4; ++q) {
          Op[(size_t)(gr + q) * NN + gc] = f32_to_bf16_rne(acc[tr][tc][q] * s);
        }
      }
    }
  } else {
#pragma unroll
    for (int tc = 0; tc < 4; ++tc) {
      const int gc = n0 + brow0 + tc * 16 + fr;
#pragma unroll
      for (int tr = 0; tr < 4; ++tr) {
        const int gr = m0 + arow0 + tr * 16 + rq;
        ushort4 pk;
        pk.x = f32_to_bf16_rne(acc[tr][tc][0]);
        pk.y = f32_to_bf16_rne(acc[tr][tc][1]);
        pk.z = f32_to_bf16_rne(acc[tr][tc][2]);
        pk.w = f32_to_bf16_rne(acc[tr][tc][3]);
        *reinterpret_cast<ushort4*>(&Op[(size_t)gc * NN + gr]) = pk;  // gr % 4 == 0
      }
    }
  }
}

// L1: 4 independent 1024^3 composes, 256 blocks.
//  PAlo  = A1*A2            = compose(A1, A2t)        (row-major)
//  PAhit = (A3*A4)^T        = composeT(A3, A4t)
//  PBhi  = B4*B3            = compose(B4, B3t)        (row-major)
//  PBlot = (B2*B1)^T        = composeT(B2, B1t)
__global__ __launch_bounds__(256) void composeL1_kernel(
    const unsigned short* __restrict__ A1, const unsigned short* __restrict__ A2t,
    const unsigned short* __restrict__ A3, const unsigned short* __restrict__ A4t,
    const unsigned short* __restrict__ B4, const unsigned short* __restrict__ B3t,
    const unsigned short* __restrict__ B2, const unsigned short* __restrict__ B1t,
    unsigned short* __restrict__ PAlo, unsigned short* __restrict__ PAhit,
    unsigned short* __restrict__ PBhi, unsigned short* __restrict__ PBlot) {
  const int sub = blockIdx.x >> 6, b = blockIdx.x & 63;
  switch (sub) {
    case 0: compose_body(A1, A2t, PAlo, nullptr, b, false); break;
    case 1: compose_body(A3, A4t, PAhit, nullptr, b, true); break;
    case 2: compose_body(B4, B3t, PBhi, nullptr, b, false); break;
    default: compose_body(B2, B1t, PBlot, nullptr, b, true); break;
  }
}

// L2: Asig = (PAlo * PAhit^T)*sigma = A*sigma ; Bt2 = PBlot * PBhi^T = B^T. 128 blocks.
__global__ __launch_bounds__(256) void composeL2_kernel(
    const unsigned short* __restrict__ PAlo, const unsigned short* __restrict__ PAhit,
    const unsigned short* __restrict__ PBhi, const unsigned short* __restrict__ PBlot,
    const float* __restrict__ sigmas,
    unsigned short* __restrict__ Asig, unsigned short* __restrict__ Bt2) {
  const int b = blockIdx.x;
  if (b < 64) compose_body(PAlo, PAhit, Asig, sigmas, b, false);
  else compose_body(PBlot, PBhi, Bt2, nullptr, b - 64, false);
}

// L3: Mt[n][k] = sum_j Bt2[n][j] * Asig[k][j]. 64 blocks.
__global__ __launch_bounds__(256) void composeMt_kernel(
    const unsigned short* __restrict__ Bt2, const unsigned short* __restrict__ Asig,
    unsigned short* __restrict__ Mt) {
  compose_body(Bt2, Asig, Mt, nullptr, blockIdx.x, false);
}

// -------------------- GEMM: out = x @ M + bias (X f32 -> bf16 on the fly) ----
__global__ __launch_bounds__(256) void gemm_kernel(
    const float* __restrict__ X, const unsigned short* __restrict__ Mt,
    const float* __restrict__ bias, float* __restrict__ Out) {
  __shared__ unsigned short As[BM * LDK];
  __shared__ unsigned short Bs[BN * LDK];
  const int tid = threadIdx.x;
  const int lane = tid & 63, wave = tid >> 6;
  const int bm = blockIdx.x & 127;
  const int bn = blockIdx.x >> 7;
  const int m0 = bm * BM, n0 = bn * BN;
  const int wm = wave & 1, wn = wave >> 1;

  const int srow = tid >> 1;
  const int scol = (tid & 1) << 4;
  const float* aptr = X + (size_t)(m0 + srow) * NN + scol;
  const unsigned short* bptr = Mt + (size_t)(n0 + srow) * NN + scol;

  f32x4 acc[4][4];
#pragma unroll
  for (int a = 0; a < 4; ++a)
#pragma unroll
    for (int b = 0; b < 4; ++b) acc[a][b] = 0.f;

  float4 ra0 = *reinterpret_cast<const float4*>(aptr + 0);
  float4 ra1 = *reinterpret_cast<const float4*>(aptr + 4);
  float4 ra2 = *reinterpret_cast<const float4*>(aptr + 8);
  float4 ra3 = *reinterpret_cast<const float4*>(aptr + 12);
  uint4 rb0 = *reinterpret_cast<const uint4*>(bptr + 0);
  uint4 rb1 = *reinterpret_cast<const uint4*>(bptr + 8);

  const int arow0 = wm * 64;
  const int brow0 = wn * 64;
  const int fr = lane & 15;
  const int kb = (lane >> 4) << 3;

#pragma unroll 1
  for (int kt = 0; kt < NN / BK; ++kt) {
    __syncthreads();
    uint4 w0, w1;
    w0.x = pack2bf(ra0.x, ra0.y); w0.y = pack2bf(ra0.z, ra0.w);
    w0.z = pack2bf(ra1.x, ra1.y); w0.w = pack2bf(ra1.z, ra1.w);
    w1.x = pack2bf(ra2.x, ra2.y); w1.y = pack2bf(ra2.z, ra2.w);
    w1.z = pack2bf(ra3.x, ra3.y); w1.w = pack2bf(ra3.z, ra3.w);
    *reinterpret_cast<uint4*>(&As[srow * LDK + scol]) = w0;
    *reinterpret_cast<uint4*>(&As[srow * LDK + scol + 8]) = w1;
    *reinterpret_cast<uint4*>(&Bs[srow * LDK + scol]) = rb0;
    *reinterpret_cast<uint4*>(&Bs[srow * LDK + scol + 8]) = rb1;
    __syncthreads();
    if (kt + 1 < NN / BK) {
      const float* ap = aptr + (kt + 1) * BK;
      const unsigned short* bp = bptr + (kt + 1) * BK;
      ra0 = *reinterpret_cast<const float4*>(ap + 0);
      ra1 = *reinterpret_cast<const float4*>(ap + 4);
      ra2 = *reinterpret_cast<const float4*>(ap + 8);
      ra3 = *reinterpret_cast<const float4*>(ap + 12);
      rb0 = *reinterpret_cast<const uint4*>(bp + 0);
      rb1 = *reinterpret_cast<const uint4*>(bp + 8);
    }
    short8 af[4], bf[4];
#pragma unroll
    for (int tr = 0; tr < 4; ++tr)
      af[tr] = *reinterpret_cast<const short8*>(&As[(arow0 + tr * 16 + fr) * LDK + kb]);
#pragma unroll
    for (int tc = 0; tc < 4; ++tc)
      bf[tc] = *reinterpret_cast<const short8*>(&Bs[(brow0 + tc * 16 + fr) * LDK + kb]);
#pragma unroll
    for (int tr = 0; tr < 4; ++tr)
#pragma unroll
      for (int tc = 0; tc < 4; ++tc)
        acc[tr][tc] = __builtin_amdgcn_mfma_f32_16x16x32_bf16(af[tr], bf[tc], acc[tr][tc], 0, 0, 0);
  }

  const int rq = (lane >> 4) << 2;
#pragma unroll
  for (int tc = 0; tc < 4; ++tc) {
    const int gc = n0 + brow0 + tc * 16 + fr;
    const float bv = bias[gc];
#pragma unroll
    for (int tr = 0; tr < 4; ++tr) {
      const int gr = m0 + arow0 + tr * 16 + rq;
#pragma unroll
      for (int q = 0; q < 4; ++q) {
        Out[(size_t)(gr + q) * NN + gc] = acc[tr][tc][q] + bv;
      }
    }
  }
}

extern "C" void kernel_launch(void* const* d_in, const int* in_sizes, int n_in,
                              void* d_out, int out_size, void* d_ws, size_t ws_size,
                              hipStream_t stream) {
  const float* x = (const float*)d_in[0];
  const float* U = (const float*)d_in[1];
  const float* V = (const float*)d_in[2];
  const float* p = (const float*)d_in[3];
  const float* bias = (const float*)d_in[4];
  float* out = (float*)d_out;

  char* ws = (char*)d_ws;
  float* tau_u = (float*)(ws);
  float* tau_v = (float*)(ws + 4096);
  float* sigmas = (float*)(ws + 8192);
  float* T8all = (float*)(ws + 16384);                 // 64 KB
  unsigned short* Mt = (unsigned short*)(ws + 81920);  // 2 MB (must survive until gemm)

  // 14 x 2MB bf16 temporaries in d_out (64 MB); all consumed before gemm writes.
  unsigned short* sc = (unsigned short*)d_out;
  const size_t ME = (size_t)NN * NN;
  unsigned short* A1    = sc + 0 * ME;
  unsigned short* B1t   = sc + 1 * ME;
  unsigned short* A2t   = sc + 2 * ME;
  unsigned short* B2    = sc + 3 * ME;
  unsigned short* A3    = sc + 4 * ME;
  unsigned short* B3t   = sc + 5 * ME;
  unsigned short* A4t   = sc + 6 * ME;
  unsigned short* B4    = sc + 7 * ME;
  unsigned short* PAlo  = sc + 8 * ME;
  unsigned short* PAhit = sc + 9 * ME;
  unsigned short* PBhi  = sc + 10 * ME;
  unsigned short* PBlot = sc + 11 * ME;
  unsigned short* Asig  = sc + 12 * ME;
  unsigned short* Bt2   = sc + 13 * ME;

  prep_kernel<<<516, 256, 0, stream>>>(U, V, p, tau_u, tau_v, sigmas);
  gram_t8_kernel<<<256, 64, 0, stream>>>(U, V, tau_u, tau_v, T8all);
  build8_kernel<<<512, 256, 0, stream>>>(U, V, T8all, A1, B1t, A2t, B2, A3, B3t, A4t, B4);
  composeL1_kernel<<<256, 256, 0, stream>>>(A1, A2t, A3, A4t, B4, B3t, B2, B1t,
                                            PAlo, PAhit, PBhi, PBlot);
  composeL2_kernel<<<128, 256, 0, stream>>>(PAlo, PAhit, PBhi, PBlot, sigmas, Asig, Bt2);
  composeMt_kernel<<<64, 256, 0, stream>>>(Bt2, Asig, Mt);
  gemm_kernel<<<1024, 256, 0, stream>>>(x, Mt, bias, out);
}

// Round 9
// 418.896 us; speedup vs baseline: 1.5666x; 1.0123x over previous
//
#include <hip/hip_runtime.h>
#include <stdint.h>

typedef __attribute__((ext_vector_type(8))) short short8;
typedef __attribute__((ext_vector_type(4))) float f32x4;
typedef __attribute__((ext_vector_type(2))) float f32x2;

#define NN 1024
#define NBATCH 16384

__device__ __forceinline__ unsigned short f32_to_bf16_rne(float f) {
  unsigned int u = __float_as_uint(f);
  unsigned int r = (u + 0x7fffu + ((u >> 16) & 1u)) >> 16;
  return (unsigned short)r;
}

__device__ __forceinline__ unsigned int pack2bf(float lo, float hi) {
  return (unsigned int)f32_to_bf16_rne(lo) | ((unsigned int)f32_to_bf16_rne(hi) << 16);
}

// 64-lane all-reduce sum. 4 DPP stages (xor1/2/4/8) then cross-row/half
// exchanges. gfx950: permlane16/32_swap are VALU -> zero LDS-pipe ops
// (the old ds_swizzle+bpermute contended with the b128 u-reads).
// Bit-identical to the old version (IEEE a+b == b+a).
__device__ __forceinline__ float allsum64(float x) {
  x += __int_as_float(__builtin_amdgcn_update_dpp(0, __float_as_int(x), 0xB1, 0xF, 0xF, true));   // xor1
  x += __int_as_float(__builtin_amdgcn_update_dpp(0, __float_as_int(x), 0x4E, 0xF, 0xF, true));   // xor2
  x += __int_as_float(__builtin_amdgcn_update_dpp(0, __float_as_int(x), 0x141, 0xF, 0xF, true));  // xor4 (row_half_mirror)
  x += __int_as_float(__builtin_amdgcn_update_dpp(0, __float_as_int(x), 0x140, 0xF, 0xF, true));  // xor8 (row_mirror)
#if __has_builtin(__builtin_amdgcn_permlane16_swap) && __has_builtin(__builtin_amdgcn_permlane32_swap)
  {
    auto r16 = __builtin_amdgcn_permlane16_swap(__float_as_uint(x), __float_as_uint(x), false, false);
    x = __uint_as_float(r16[0]) + __uint_as_float(r16[1]);  // xor16
    auto r32 = __builtin_amdgcn_permlane32_swap(__float_as_uint(x), __float_as_uint(x), false, false);
    x = __uint_as_float(r32[0]) + __uint_as_float(r32[1]);  // xor32
  }
#else
  x += __int_as_float(__builtin_amdgcn_ds_swizzle(__float_as_int(x), 0x401F));                    // xor16
  x += __shfl_xor(x, 32);
#endif
  return x;
}

// -------------------- prep: tau = 2/(u.u), sigmas --------------------
__global__ __launch_bounds__(256) void prep_kernel(
    const float* __restrict__ U, const float* __restrict__ V,
    const float* __restrict__ p, float* __restrict__ tau_u,
    float* __restrict__ tau_v, float* __restrict__ sigmas) {
  int wave = threadIdx.x >> 6, lane = threadIdx.x & 63;
  int row = blockIdx.x * 4 + wave;
  if (row < 2048) {
    const float* u = (row < NN) ? (U + (size_t)row * NN) : (V + (size_t)(row - NN) * NN);
    float s = 0.f;
#pragma unroll
    for (int t = 0; t < 16; ++t) { float a = u[lane + (t << 6)]; s += a * a; }
    s = allsum64(s);
    if (lane == 0) {
      float tau = 2.0f / s;
      if (row < NN) tau_u[row] = tau;
      else tau_v[row - NN] = tau;
    }
  } else if (row < 2064) {
    int j = ((row - 2048) << 6) + lane;
    float pj = p[j];
    float sg = 1.0f / (1.0f + expf(-pj));
    sigmas[j] = 0.9f * (sg - 0.5f) + 0.55f;  // r=0.45, mean=0.55
  }
}

// -------------------- gram + T8 per block of 8 reflectors --------------------
// blk<128: U bank, rows 8*blk+j (j=0..7). blk>=128: s=blk-128, V bank, rows 1023-8s-j.
__global__ __launch_bounds__(64) void gram_t8_kernel(
    const float* __restrict__ U, const float* __restrict__ V,
    const float* __restrict__ tau_u, const float* __restrict__ tau_v,
    float* __restrict__ T8all) {
  __shared__ float G[64];
  const int blk = blockIdx.x;
  const int lane = threadIdx.x;
  const float* bank;
  int rbase, rsign, st;
  if (blk < 128) { bank = U; rbase = 8 * blk; rsign = 1; st = 8 * blk; }
  else { int s = blk - 128; bank = V; rbase = 1023 - 8 * s; rsign = -1; st = 1016 - 8 * s; }

  if (lane < 28) {
    int j = 1, k = 0, t = lane;
    for (int jj = 1; jj < 8; ++jj) {
      int lo = jj * (jj - 1) / 2, hi = jj * (jj + 1) / 2;
      if (t >= lo && t < hi) { j = jj; k = t - lo; }
    }
    const float* rk = bank + (size_t)(rbase + rsign * k) * NN;
    const float* rj = bank + (size_t)(rbase + rsign * j) * NN;
    float acc = 0.f;
    for (int i = st >> 2; i < 256; ++i) {
      float4 a = *reinterpret_cast<const float4*>(rk + 4 * i);
      float4 b = *reinterpret_cast<const float4*>(rj + 4 * i);
      acc += a.x * b.x + a.y * b.y + a.z * b.z + a.w * b.w;
    }
    G[k * 8 + j] = acc;
  }
  __syncthreads();

  if (lane < 8) {
    float Tr[8];
#pragma unroll
    for (int j = 0; j < 8; ++j) Tr[j] = 0.f;
#pragma unroll
    for (int j = 0; j < 8; ++j) {
      int grow = rbase + rsign * j;
      float tj = (blk < 128) ? tau_u[grow] : tau_v[grow];
      float a = 0.f;
#pragma unroll
      for (int k = 0; k < 8; ++k) {
        if (k < j) a += Tr[k] * G[k * 8 + j];
      }
      Tr[j] = (lane == j) ? tj : (-tj * a);
    }
#pragma unroll
    for (int j = 0; j < 8; ++j) T8all[(size_t)blk * 64 + lane * 8 + j] = Tr[j];
  }
}

// -------------------- build 8 quarter-chains: 512 blocks x 256 threads, 4 rows/wave ----
// Logical chains: c=0:A1, 1:B1, 2:A2, 3:B2, 4:A3, 5:B3, 6:A4, 7:B4.  Q0 = c>>1.
// Block->chain remap for CU balance: cg = bid>>6; c = cg<4 ? cg : cg^2, so the
// round-robin pairs per CU are (Q0=0,Q0=3) or (Q0=1,Q0=2) = constant 5 units.
// A_k = H_u(256k)..H_u(256k+255) asc.  B_k = H_v(256k+255)..H_v(256k) desc.
// Store: A1,B2,A3,B4 row-major; B1,A2,B3,A4 transposed.
// Element map: v[r][2q+(e>>1)][e&1] holds element 256q+4lane+e of row row0+r.
__device__ __forceinline__ void stage8(int c, int step, float* lbuf, float* tbuf,
    const float* __restrict__ U, const float* __restrict__ V,
    const float* __restrict__ T8all, int wave, int lane) {
  if (step >= 32) return;
  const int k = c >> 1;
  const int q0 = k;
  int rbase, rsign, t8i;
  const float* bank;
  if ((c & 1) == 0) {  // U side
    bank = U; rbase = 256 * k + 8 * step; rsign = 1; t8i = 32 * k + step;
  } else {             // V side, descending
    int s = (96 - 32 * k) + step;
    bank = V; rbase = 1023 - 8 * s; rsign = -1; t8i = 128 + s;
  }
#pragma unroll
  for (int cc = 0; cc < 8; ++cc) {
    const int chunk = (wave << 3) + cc;  // 4 waves x 8 chunks = 8 slots x 4 quarters
    const int slot = chunk >> 2, q = chunk & 3;
    if (q < q0) continue;
    const int grow = rbase + rsign * slot;
    const float* gsrc = bank + (size_t)grow * NN + q * 256 + lane * 4;
    float* ldst = lbuf + slot * NN + q * 256;
    __builtin_amdgcn_global_load_lds(
        (const __attribute__((address_space(1))) void*)gsrc,
        (__attribute__((address_space(3))) void*)ldst, 16, 0, 0);
  }
  if (wave == 0 && lane < 16) {
    float4 t = *reinterpret_cast<const float4*>(T8all + (size_t)t8i * 64 + lane * 4);
    *reinterpret_cast<float4*>(tbuf + lane * 4) = t;
  }
}

// Two-pass WY-8 on FOUR rows per wave, packed-f32 (v_pk_fma_f32) arithmetic.
template <int Q0>
__device__ __forceinline__ void apply_block4(const float* __restrict__ ub,
    const float* __restrict__ tb, f32x2 v[4][8], int lane) {
  float c[4][8];
  // pass 1: dots (packed)
#pragma unroll
  for (int j = 0; j < 8; ++j) {
    f32x2 a0 = {0.f, 0.f}, a1 = {0.f, 0.f}, a2 = {0.f, 0.f}, a3 = {0.f, 0.f};
#pragma unroll
    for (int q = Q0; q < 4; ++q) {
      const float4 uu = *reinterpret_cast<const float4*>(&ub[j * NN + q * 256 + lane * 4]);
      const f32x2 u0 = {uu.x, uu.y}, u1 = {uu.z, uu.w};
      a0 += u0 * v[0][2 * q] + u1 * v[0][2 * q + 1];
      a1 += u0 * v[1][2 * q] + u1 * v[1][2 * q + 1];
      a2 += u0 * v[2][2 * q] + u1 * v[2][2 * q + 1];
      a3 += u0 * v[3][2 * q] + u1 * v[3][2 * q + 1];
    }
    c[0][j] = a0[0] + a0[1]; c[1][j] = a1[0] + a1[1];
    c[2][j] = a2[0] + a2[1]; c[3][j] = a3[0] + a3[1];
  }
#pragma unroll
  for (int r = 0; r < 4; ++r)
#pragma unroll
    for (int j = 0; j < 8; ++j) c[r][j] = allsum64(c[r][j]);
  // w = c * T (T upper-tri), in place descending j: c[r][k<j] still original.
#pragma unroll
  for (int j = 7; j >= 0; --j) {
#pragma unroll
    for (int r = 0; r < 4; ++r) {
      float acc = 0.f;
#pragma unroll
      for (int k = 0; k < 8; ++k) {
        if (k <= j) acc += c[r][k] * tb[k * 8 + j];
      }
      c[r][j] = acc;
    }
  }
  // pass 2: update (packed; re-read u from LDS)
#pragma unroll
  for (int q = Q0; q < 4; ++q) {
#pragma unroll
    for (int j = 0; j < 8; ++j) {
      const float4 uu = *reinterpret_cast<const float4*>(&ub[j * NN + q * 256 + lane * 4]);
      const f32x2 u0 = {uu.x, uu.y}, u1 = {uu.z, uu.w};
#pragma unroll
      for (int r = 0; r < 4; ++r) {
        const f32x2 ws = {c[r][j], c[r][j]};
        v[r][2 * q]     -= ws * u0;
        v[r][2 * q + 1] -= ws * u1;
      }
    }
  }
}

__global__ __launch_bounds__(256) void build8_kernel(
    const float* __restrict__ U, const float* __restrict__ V,
    const float* __restrict__ T8all,
    unsigned short* __restrict__ A1, unsigned short* __restrict__ B1t,
    unsigned short* __restrict__ A2t, unsigned short* __restrict__ B2,
    unsigned short* __restrict__ A3, unsigned short* __restrict__ B3t,
    unsigned short* __restrict__ A4t, unsigned short* __restrict__ B4) {
  __shared__ float ubuf[2][8 * NN];
  __shared__ float tbuf[2][64];
  const int tid = threadIdx.x;
  const int wave = tid >> 6, lane = tid & 63;
  const int cg = blockIdx.x >> 6;
  const int c = (cg < 4) ? cg : (cg ^ 2);  // balance: CU pairs sum to 5 units
  const int row0 = ((blockIdx.x & 63) << 4) + (wave << 2);

  f32x2 v[4][8];
#pragma unroll
  for (int q = 0; q < 4; ++q)
#pragma unroll
    for (int e = 0; e < 4; ++e) {
      const int el = 256 * q + 4 * lane + e;
#pragma unroll
      for (int r = 0; r < 4; ++r)
        v[r][2 * q + (e >> 1)][e & 1] = (el == row0 + r) ? 1.0f : 0.0f;
    }

  stage8(c, 0, ubuf[0], tbuf[0], U, V, T8all, wave, lane);
  int pb = 0;

#define CHAIN_LOOP(Q0C)                                                          \
  for (int s = 0; s < 32; ++s) {                                                 \
    __syncthreads(); /* vmcnt drained: staged buf ready, prev buf consumed */    \
    stage8(c, s + 1, ubuf[pb ^ 1], tbuf[pb ^ 1], U, V, T8all, wave, lane);       \
    apply_block4<Q0C>(ubuf[pb], tbuf[pb], v, lane);                              \
    pb ^= 1;                                                                     \
  }
  switch (c >> 1) {
    case 0: CHAIN_LOOP(0) break;
    case 1: CHAIN_LOOP(1) break;
    case 2: CHAIN_LOOP(2) break;
    default: CHAIN_LOOP(3) break;
  }
#undef CHAIN_LOOP

  unsigned short* dst;
  bool rm;
  switch (c) {
    case 0:  dst = A1;  rm = true;  break;
    case 1:  dst = B1t; rm = false; break;
    case 2:  dst = A2t; rm = false; break;
    case 3:  dst = B2;  rm = true;  break;
    case 4:  dst = A3;  rm = true;  break;
    case 5:  dst = B3t; rm = false; break;
    case 6:  dst = A4t; rm = false; break;
    default: dst = B4;  rm = true;  break;
  }
  if (rm) {
#pragma unroll
    for (int r = 0; r < 4; ++r) {
#pragma unroll
      for (int q = 0; q < 4; ++q) {
        ushort4 pk;
        pk.x = f32_to_bf16_rne(v[r][2 * q][0]);
        pk.y = f32_to_bf16_rne(v[r][2 * q][1]);
        pk.z = f32_to_bf16_rne(v[r][2 * q + 1][0]);
        pk.w = f32_to_bf16_rne(v[r][2 * q + 1][1]);
        *reinterpret_cast<ushort4*>(&dst[(size_t)(row0 + r) * NN + 256 * q + 4 * lane]) = pk;
      }
    }
  } else {
#pragma unroll
    for (int q = 0; q < 4; ++q)
#pragma unroll
      for (int e = 0; e < 4; ++e) {
        const size_t el = 256 * q + 4 * lane + e;
        ushort4 pk;
        pk.x = f32_to_bf16_rne(v[0][2 * q + (e >> 1)][e & 1]);
        pk.y = f32_to_bf16_rne(v[1][2 * q + (e >> 1)][e & 1]);
        pk.z = f32_to_bf16_rne(v[2][2 * q + (e >> 1)][e & 1]);
        pk.w = f32_to_bf16_rne(v[3][2 * q + (e >> 1)][e & 1]);
        *reinterpret_cast<ushort4*>(&dst[el * NN + row0]) = pk;  // row0 % 4 == 0
      }
  }
}

// -------------------- generic 1024^3 bf16 compose: D[m][n] = sum_k X[m][k]*W[n][k] ----
// tstore: write D transposed (Op[n][m]) via per-lane ushort4 over the 4 m-values.
#define BM 128
#define BN 128
#define BK 32
#define LDK 40

__device__ __forceinline__ void compose_body(
    const unsigned short* __restrict__ Xb, const unsigned short* __restrict__ Wb,
    unsigned short* __restrict__ Op, const float* __restrict__ sig, int b, bool tstore) {
  __shared__ unsigned short As[BM * LDK];
  __shared__ unsigned short Bs[BN * LDK];
  const int tid = threadIdx.x;
  const int lane = tid & 63, wave = tid >> 6;
  const int bm = b & 7, bn = b >> 3;
  const int m0 = bm * BM, n0 = bn * BN;
  const int wm = wave & 1, wn = wave >> 1;

  const int srow = tid >> 1;
  const int scol = (tid & 1) << 4;
  const unsigned short* aptr = Xb + (size_t)(m0 + srow) * NN + scol;
  const unsigned short* bptr = Wb + (size_t)(n0 + srow) * NN + scol;

  f32x4 acc[4][4];
#pragma unroll
  for (int a = 0; a < 4; ++a)
#pragma unroll
    for (int bb = 0; bb < 4; ++bb) acc[a][bb] = 0.f;

  uint4 ra0 = *reinterpret_cast<const uint4*>(aptr + 0);
  uint4 ra1 = *reinterpret_cast<const uint4*>(aptr + 8);
  uint4 rb0 = *reinterpret_cast<const uint4*>(bptr + 0);
  uint4 rb1 = *reinterpret_cast<const uint4*>(bptr + 8);

  const int arow0 = wm * 64;
  const int brow0 = wn * 64;
  const int fr = lane & 15;
  const int kb = (lane >> 4) << 3;

#pragma unroll 1
  for (int kt = 0; kt < NN / BK; ++kt) {
    __syncthreads();
    *reinterpret_cast<uint4*>(&As[srow * LDK + scol]) = ra0;
    *reinterpret_cast<uint4*>(&As[srow * LDK + scol + 8]) = ra1;
    *reinterpret_cast<uint4*>(&Bs[srow * LDK + scol]) = rb0;
    *reinterpret_cast<uint4*>(&Bs[srow * LDK + scol + 8]) = rb1;
    __syncthreads();
    if (kt + 1 < NN / BK) {
      const unsigned short* ap = aptr + (kt + 1) * BK;
      const unsigned short* bp = bptr + (kt + 1) * BK;
      ra0 = *reinterpret_cast<const uint4*>(ap + 0);
      ra1 = *reinterpret_cast<const uint4*>(ap + 8);
      rb0 = *reinterpret_cast<const uint4*>(bp + 0);
      rb1 = *reinterpret_cast<const uint4*>(bp + 8);
    }
    short8 af[4], bf[4];
#pragma unroll
    for (int tr = 0; tr < 4; ++tr)
      af[tr] = *reinterpret_cast<const short8*>(&As[(arow0 + tr * 16 + fr) * LDK + kb]);
#pragma unroll
    for (int tc = 0; tc < 4; ++tc)
      bf[tc] = *reinterpret_cast<const short8*>(&Bs[(brow0 + tc * 16 + fr) * LDK + kb]);
#pragma unroll
    for (int tr = 0; tr < 4; ++tr)
#pragma unroll
      for (int tc = 0; tc < 4; ++tc)
        acc[tr][tc] = __builtin_amdgcn_mfma_f32_16x16x32_bf16(af[tr], bf[tc], acc[tr][tc], 0, 0, 0);
  }

  const int rq = (lane >> 4) << 2;
  if (!tstore) {
#pragma unroll
    for (int tc = 0; tc < 4; ++tc) {
      const int gc = n0 + brow0 + tc * 16 + fr;
      const float s = sig ? sig[gc] : 1.0f;
#pragma unroll
      for (int tr = 0; tr < 4; ++tr) {
        const int gr = m0 + arow0 + tr * 16 + rq;
#pragma unroll
        for (int q = 0; q < 4; ++q) {
          Op[(size_t)(gr + q) * NN + gc] = f32_to_bf16_rne(acc[tr][tc][q] * s);
        }
      }
    }
  } else {
#pragma unroll
    for (int tc = 0; tc < 4; ++tc) {
      const int gc = n0 + brow0 + tc * 16 + fr;
#pragma unroll
      for (int tr = 0; tr < 4; ++tr) {
        const int gr = m0 + arow0 + tr * 16 + rq;
        ushort4 pk;
        pk.x = f32_to_bf16_rne(acc[tr][tc][0]);
        pk.y = f32_to_bf16_rne(acc[tr][tc][1]);
        pk.z = f32_to_bf16_rne(acc[tr][tc][2]);
        pk.w = f32_to_bf16_rne(acc[tr][tc][3]);
        *reinterpret_cast<ushort4*>(&Op[(size_t)gc * NN + gr]) = pk;  // gr % 4 == 0
      }
    }
  }
}

// L1: 4 independent 1024^3 composes, 256 blocks.
__global__ __launch_bounds__(256) void composeL1_kernel(
    const unsigned short* __restrict__ A1, const unsigned short* __restrict__ A2t,
    const unsigned short* __restrict__ A3, const unsigned short* __restrict__ A4t,
    const unsigned short* __restrict__ B4, const unsigned short* __restrict__ B3t,
    const unsigned short* __restrict__ B2, const unsigned short* __restrict__ B1t,
    unsigned short* __restrict__ PAlo, unsigned short* __restrict__ PAhit,
    unsigned short* __restrict__ PBhi, unsigned short* __restrict__ PBlot) {
  const int sub = blockIdx.x >> 6, b = blockIdx.x & 63;
  switch (sub) {
    case 0: compose_body(A1, A2t, PAlo, nullptr, b, false); break;
    case 1: compose_body(A3, A4t, PAhit, nullptr, b, true); break;
    case 2: compose_body(B4, B3t, PBhi, nullptr, b, false); break;
    default: compose_body(B2, B1t, PBlot, nullptr, b, true); break;
  }
}

// L2: Asig = (PAlo * PAhit^T)*sigma ; Bt2 = PBlot * PBhi^T. 128 blocks.
__global__ __launch_bounds__(256) void composeL2_kernel(
    const unsigned short* __restrict__ PAlo, const unsigned short* __restrict__ PAhit,
    const unsigned short* __restrict__ PBhi, const unsigned short* __restrict__ PBlot,
    const float* __restrict__ sigmas,
    unsigned short* __restrict__ Asig, unsigned short* __restrict__ Bt2) {
  const int b = blockIdx.x;
  if (b < 64) compose_body(PAlo, PAhit, Asig, sigmas, b, false);
  else compose_body(PBlot, PBhi, Bt2, nullptr, b - 64, false);
}

// L3: Mt[n][k] = sum_j Bt2[n][j] * Asig[k][j]. 64 blocks.
__global__ __launch_bounds__(256) void composeMt_kernel(
    const unsigned short* __restrict__ Bt2, const unsigned short* __restrict__ Asig,
    unsigned short* __restrict__ Mt) {
  compose_body(Bt2, Asig, Mt, nullptr, blockIdx.x, false);
}

// -------------------- GEMM: out = x @ M + bias (X f32 -> bf16 on the fly) ----
__global__ __launch_bounds__(256) void gemm_kernel(
    const float* __restrict__ X, const unsigned short* __restrict__ Mt,
    const float* __restrict__ bias, float* __restrict__ Out) {
  __shared__ unsigned short As[BM * LDK];
  __shared__ unsigned short Bs[BN * LDK];
  const int tid = threadIdx.x;
  const int lane = tid & 63, wave = tid >> 6;
  const int bm = blockIdx.x & 127;
  const int bn = blockIdx.x >> 7;
  const int m0 = bm * BM, n0 = bn * BN;
  const int wm = wave & 1, wn = wave >> 1;

  const int srow = tid >> 1;
  const int scol = (tid & 1) << 4;
  const float* aptr = X + (size_t)(m0 + srow) * NN + scol;
  const unsigned short* bptr = Mt + (size_t)(n0 + srow) * NN + scol;

  f32x4 acc[4][4];
#pragma unroll
  for (int a = 0; a < 4; ++a)
#pragma unroll
    for (int b = 0; b < 4; ++b) acc[a][b] = 0.f;

  float4 ra0 = *reinterpret_cast<const float4*>(aptr + 0);
  float4 ra1 = *reinterpret_cast<const float4*>(aptr + 4);
  float4 ra2 = *reinterpret_cast<const float4*>(aptr + 8);
  float4 ra3 = *reinterpret_cast<const float4*>(aptr + 12);
  uint4 rb0 = *reinterpret_cast<const uint4*>(bptr + 0);
  uint4 rb1 = *reinterpret_cast<const uint4*>(bptr + 8);

  const int arow0 = wm * 64;
  const int brow0 = wn * 64;
  const int fr = lane & 15;
  const int kb = (lane >> 4) << 3;

#pragma unroll 1
  for (int kt = 0; kt < NN / BK; ++kt) {
    __syncthreads();
    uint4 w0, w1;
    w0.x = pack2bf(ra0.x, ra0.y); w0.y = pack2bf(ra0.z, ra0.w);
    w0.z = pack2bf(ra1.x, ra1.y); w0.w = pack2bf(ra1.z, ra1.w);
    w1.x = pack2bf(ra2.x, ra2.y); w1.y = pack2bf(ra2.z, ra2.w);
    w1.z = pack2bf(ra3.x, ra3.y); w1.w = pack2bf(ra3.z, ra3.w);
    *reinterpret_cast<uint4*>(&As[srow * LDK + scol]) = w0;
    *reinterpret_cast<uint4*>(&As[srow * LDK + scol + 8]) = w1;
    *reinterpret_cast<uint4*>(&Bs[srow * LDK + scol]) = rb0;
    *reinterpret_cast<uint4*>(&Bs[srow * LDK + scol + 8]) = rb1;
    __syncthreads();
    if (kt + 1 < NN / BK) {
      const float* ap = aptr + (kt + 1) * BK;
      const unsigned short* bp = bptr + (kt + 1) * BK;
      ra0 = *reinterpret_cast<const float4*>(ap + 0);
      ra1 = *reinterpret_cast<const float4*>(ap + 4);
      ra2 = *reinterpret_cast<const float4*>(ap + 8);
      ra3 = *reinterpret_cast<const float4*>(ap + 12);
      rb0 = *reinterpret_cast<const uint4*>(bp + 0);
      rb1 = *reinterpret_cast<const uint4*>(bp + 8);
    }
    short8 af[4], bf[4];
#pragma unroll
    for (int tr = 0; tr < 4; ++tr)
      af[tr] = *reinterpret_cast<const short8*>(&As[(arow0 + tr * 16 + fr) * LDK + kb]);
#pragma unroll
    for (int tc = 0; tc < 4; ++tc)
      bf[tc] = *reinterpret_cast<const short8*>(&Bs[(brow0 + tc * 16 + fr) * LDK + kb]);
#pragma unroll
    for (int tr = 0; tr < 4; ++tr)
#pragma unroll
      for (int tc = 0; tc < 4; ++tc)
        acc[tr][tc] = __builtin_amdgcn_mfma_f32_16x16x32_bf16(af[tr], bf[tc], acc[tr][tc], 0, 0, 0);
  }

  const int rq = (lane >> 4) << 2;
#pragma unroll
  for (int tc = 0; tc < 4; ++tc) {
    const int gc = n0 + brow0 + tc * 16 + fr;
    const float bv = bias[gc];
#pragma unroll
    for (int tr = 0; tr < 4; ++tr) {
      const int gr = m0 + arow0 + tr * 16 + rq;
#pragma unroll
      for (int q = 0; q < 4; ++q) {
        Out[(size_t)(gr + q) * NN + gc] = acc[tr][tc][q] + bv;
      }
    }
  }
}

extern "C" void kernel_launch(void* const* d_in, const int* in_sizes, int n_in,
                              void* d_out, int out_size, void* d_ws, size_t ws_size,
                              hipStream_t stream) {
  const float* x = (const float*)d_in[0];
  const float* U = (const float*)d_in[1];
  const float* V = (const float*)d_in[2];
  const float* p = (const float*)d_in[3];
  const float* bias = (const float*)d_in[4];
  float* out = (float*)d_out;

  char* ws = (char*)d_ws;
  float* tau_u = (float*)(ws);
  float* tau_v = (float*)(ws + 4096);
  float* sigmas = (float*)(ws + 8192);
  float* T8all = (float*)(ws + 16384);                 // 64 KB
  unsigned short* Mt = (unsigned short*)(ws + 81920);  // 2 MB (must survive until gemm)

  // 14 x 2MB bf16 temporaries in d_out (64 MB); all consumed before gemm writes.
  unsigned short* sc = (unsigned short*)d_out;
  const size_t ME = (size_t)NN * NN;
  unsigned short* A1    = sc + 0 * ME;
  unsigned short* B1t   = sc + 1 * ME;
  unsigned short* A2t   = sc + 2 * ME;
  unsigned short* B2    = sc + 3 * ME;
  unsigned short* A3    = sc + 4 * ME;
  unsigned short* B3t   = sc + 5 * ME;
  unsigned short* A4t   = sc + 6 * ME;
  unsigned short* B4    = sc + 7 * ME;
  unsigned short* PAlo  = sc + 8 * ME;
  unsigned short* PAhit = sc + 9 * ME;
  unsigned short* PBhi  = sc + 10 * ME;
  unsigned short* PBlot = sc + 11 * ME;
  unsigned short* Asig  = sc + 12 * ME;
  unsigned short* Bt2   = sc + 13 * ME;

  prep_kernel<<<516, 256, 0, stream>>>(U, V, p, tau_u, tau_v, sigmas);
  gram_t8_kernel<<<256, 64, 0, stream>>>(U, V, tau_u, tau_v, T8all);
  build8_kernel<<<512, 256, 0, stream>>>(U, V, T8all, A1, B1t, A2t, B2, A3, B3t, A4t, B4);
  composeL1_kernel<<<256, 256, 0, stream>>>(A1, A2t, A3, A4t, B4, B3t, B2, B1t,
                                            PAlo, PAhit, PBhi, PBlot);
  composeL2_kernel<<<128, 256, 0, stream>>>(PAlo, PAhit, PBhi, PBlot, sigmas, Asig, Bt2);
  composeMt_kernel<<<64, 256, 0, stream>>>(Bt2, Asig, Mt);
  gemm_kernel<<<1024, 256, 0, stream>>>(x, Mt, bias, out);
}